// Round 3
// baseline (2687.929 us; speedup 1.0000x reference)
//
#include <hip/hip_runtime.h>

#define DEVI __device__ __forceinline__

typedef float  f32x4  __attribute__((ext_vector_type(4)));
typedef __bf16 bf16x8 __attribute__((ext_vector_type(8)));
typedef unsigned short u16x8 __attribute__((ext_vector_type(8)));

// ---------- helpers ----------
DEVI unsigned short f2bf(float f) {
    unsigned u = __builtin_bit_cast(unsigned, f);
    unsigned r = (u + 0x7fffu + ((u >> 16) & 1u)) >> 16;
    return (unsigned short)r;
}
DEVI float bf2f(unsigned short s) {
    return __builtin_bit_cast(float, (unsigned)s << 16);
}
DEVI u16x8 pack8(float4 a, float4 b) {
    u16x8 p;
    p[0] = f2bf(a.x); p[1] = f2bf(a.y); p[2] = f2bf(a.z); p[3] = f2bf(a.w);
    p[4] = f2bf(b.x); p[5] = f2bf(b.y); p[6] = f2bf(b.z); p[7] = f2bf(b.w);
    return p;
}
DEVI f32x4 mfma16(u16x8 a, u16x8 b, f32x4 c) {
    return __builtin_amdgcn_mfma_f32_16x16x32_bf16(
        __builtin_bit_cast(bf16x8, a), __builtin_bit_cast(bf16x8, b), c, 0, 0, 0);
}
DEVI float sigm(float x)   { return 1.f / (1.f + __expf(-x)); }
DEVI float tanh_f(float x) { return 1.f - 2.f / (1.f + __expf(2.f * x)); }

// dims
#define Hh 256
#define Bb 64
#define Tt 1024
#define MROWS (Bb * Tt)   // 65536

// ---------- K0: hp[b][k] = sum_h hidden[b][h] * W_w[k][h] (first H cols) ----------
__global__ __launch_bounds__(256) void hp_kernel(const float* __restrict__ hid,
                                                 const float* __restrict__ Ww,
                                                 float* __restrict__ hp) {
    int b = blockIdx.x, k = threadIdx.x;
    __shared__ __align__(16) float hs[Hh];
    hs[k] = hid[b * Hh + k];
    __syncthreads();
    const float4* w4 = (const float4*)(Ww + (size_t)k * 512);
    const float4* h4 = (const float4*)hs;
    float acc = 0.f;
#pragma unroll 8
    for (int i = 0; i < 64; i++) {
        float4 a = w4[i], x = h4[i];
        acc += a.x * x.x + a.y * x.y + a.z * x.z + a.w * x.w;
    }
    hp[b * Hh + k] = acc;
}

// ---------- GEMM: OUT = epilogue( A(65536x256) @ W^T )  BM=128 BN=64 K=256 ----------
// EPI 0: z = tanh(acc + hp[b][c] + W_b[c]) -> bf16 [r][c]
// EPI 1: scores = acc + V_b[c]            -> f32  [r][c]
// EPI 2: xproj  = acc + b_i[c]            -> bf16 [mat][t][b][c]
template <int EPI, bool ABF16>
__global__ __launch_bounds__(512) void gemm_k(
    const void* __restrict__ Aab,
    const float* __restrict__ W0, const float* __restrict__ W1, const float* __restrict__ W2,
    int wstride, int wcoloff,
    const float* __restrict__ bv0, const float* __restrict__ bv1, const float* __restrict__ bv2,
    const float* __restrict__ hp, const float* __restrict__ Wb,
    void* __restrict__ outv) {
    __shared__ __align__(16) unsigned short As[128 * 256];
    __shared__ __align__(16) unsigned short Bs[64 * 256];

    int tid = threadIdx.x;
    int bx = blockIdx.x, by = blockIdx.y;
    int mat = (EPI == 2) ? (by >> 2) : 0;
    int cb  = (EPI == 2) ? (by & 3) : by;
    int rowBase = bx * 128, colBase = cb * 64;
    const float* W  = (mat == 0) ? W0 : ((mat == 1) ? W1 : W2);
    const float* bv = (mat == 0) ? bv0 : ((mat == 1) ? bv1 : bv2);

    // stage A: 128 rows x 32 chunks(16B), swizzled g ^= (r&7)
    if (ABF16) {
        const unsigned short* A = (const unsigned short*)Aab;
#pragma unroll
        for (int i = 0; i < 8; i++) {
            int idx = i * 512 + tid, r = idx >> 5, g = idx & 31, gs = g ^ (r & 7);
            *(uint4*)&As[r * 256 + gs * 8] =
                *(const uint4*)(A + (((size_t)(rowBase + r)) << 8) + g * 8);
        }
    } else {
        const float* A = (const float*)Aab;
#pragma unroll
        for (int i = 0; i < 8; i++) {
            int idx = i * 512 + tid, r = idx >> 5, g = idx & 31, gs = g ^ (r & 7);
            const float* s = A + (((size_t)(rowBase + r)) << 8) + g * 8;
            float4 f0 = *(const float4*)s, f1 = *(const float4*)(s + 4);
            *(u16x8*)&As[r * 256 + gs * 8] = pack8(f0, f1);
        }
    }
    // stage B: 64 W-rows (output cols) x 32 chunks
#pragma unroll
    for (int i = 0; i < 4; i++) {
        int idx = i * 512 + tid, r = idx >> 5, g = idx & 31, gs = g ^ (r & 7);
        const float* s = W + (size_t)(colBase + r) * wstride + wcoloff + g * 8;
        float4 f0 = *(const float4*)s, f1 = *(const float4*)(s + 4);
        *(u16x8*)&Bs[r * 256 + gs * 8] = pack8(f0, f1);
    }
    __syncthreads();

    int wid = tid >> 6, lane = tid & 63, l15 = lane & 15, grp = lane >> 4;
    int wr = (wid >> 1) * 32, wc = (wid & 1) * 32;
    f32x4 acc[2][2] = {};
#pragma unroll
    for (int kc = 0; kc < 8; kc++) {
        u16x8 a[2], bb[2];
#pragma unroll
        for (int rt = 0; rt < 2; rt++) {
            int r = wr + rt * 16 + l15;
            int gs = (kc * 4 + grp) ^ (r & 7);
            a[rt] = *(const u16x8*)&As[r * 256 + gs * 8];
        }
#pragma unroll
        for (int ct = 0; ct < 2; ct++) {
            int r = wc + ct * 16 + l15;
            int gs = (kc * 4 + grp) ^ (r & 7);
            bb[ct] = *(const u16x8*)&Bs[r * 256 + gs * 8];
        }
#pragma unroll
        for (int rt = 0; rt < 2; rt++)
#pragma unroll
            for (int ct = 0; ct < 2; ct++)
                acc[rt][ct] = mfma16(a[rt], bb[ct], acc[rt][ct]);
    }
    // epilogue: D row = (lane>>4)*4 + i, col = lane&15
#pragma unroll
    for (int rt = 0; rt < 2; rt++)
#pragma unroll
        for (int ct = 0; ct < 2; ct++)
#pragma unroll
            for (int i = 0; i < 4; i++) {
                int rl = wr + rt * 16 + grp * 4 + i;
                int cl = wc + ct * 16 + l15;
                size_t r = (size_t)rowBase + rl;
                int c = colBase + cl;
                float v = acc[rt][ct][i];
                if (EPI == 0) {
                    v = tanh_f(v + hp[(r >> 10) * 256 + c] + Wb[c]);
                    ((unsigned short*)outv)[r * 256 + c] = f2bf(v);
                } else if (EPI == 1) {
                    ((float*)outv)[r * 256 + c] = v + bv[c];
                } else {
                    size_t t = r & 1023, b = r >> 10;
                    ((unsigned short*)outv)[(size_t)mat * 16777216 + (t * 64 + b) * 256 + c] =
                        f2bf(v + bv[c]);
                }
            }
}

// ---------- softmax over T, pass 1: per (b,k) online max/sumexp over a T-chunk ----------
__global__ __launch_bounds__(256) void softmax_pass1(const float* __restrict__ scores,
                                                     float* __restrict__ partMS) {
    int b = blockIdx.x, tc = blockIdx.y, k = threadIdx.x;
    const float* p = scores + ((size_t)b * Tt + tc * 128) * Hh + k;
    float m = -1e30f, S = 0.f;
    for (int i = 0; i < 128; i++) {
        float s = p[(size_t)i * Hh];
        float mn = fmaxf(m, s);
        S = S * __expf(m - mn) + __expf(s - mn);
        m = mn;
    }
    int idx = (b * 8 + tc) * Hh + k;
    partMS[idx * 2] = m;
    partMS[idx * 2 + 1] = S;
}

// ---------- softmax pass 2: combine partials, emit ctx (bf16) and x_attn ----------
__global__ __launch_bounds__(256) void softmax_pass2(const float* __restrict__ scores,
                                                     const float* __restrict__ partMS,
                                                     unsigned short* __restrict__ ctx,
                                                     float* __restrict__ x_attn) {
    int b = blockIdx.x, tc = blockIdx.y;
    int tid = threadIdx.x, w = tid >> 6, lane = tid & 63;
    float mj[4], Sj[4];
#pragma unroll
    for (int j = 0; j < 4; j++) {
        int k = lane + j * 64;
        float m = -1e30f;
#pragma unroll
        for (int c = 0; c < 8; c++)
            m = fmaxf(m, partMS[((b * 8 + c) * Hh + k) * 2]);
        float S = 0.f;
#pragma unroll
        for (int c = 0; c < 8; c++) {
            int idx = (b * 8 + c) * Hh + k;
            S += partMS[idx * 2 + 1] * __expf(partMS[idx * 2] - m);
        }
        mj[j] = m;
        Sj[j] = 1.f / S;
    }
    for (int i = 0; i < 32; i++) {
        int t = tc * 128 + w * 32 + i;
        const float* sp = scores + ((size_t)b * Tt + t) * Hh;
        unsigned short* cp = ctx + ((size_t)b * Tt + t) * Hh;
        float accsm = 0.f;
#pragma unroll
        for (int j = 0; j < 4; j++) {
            int k = lane + j * 64;
            float s = sp[k];
            float sm = __expf(s - mj[j]) * Sj[j];
            accsm += sm;
            cp[k] = f2bf(s * sm);
        }
#pragma unroll
        for (int o = 32; o >= 1; o >>= 1) accsm += __shfl_xor(accsm, o, 64);
        if (lane == 0) x_attn[b * Tt + t] = accsm;
    }
}

// ---------- GRU scan: one block per batch row, weights in registers ----------
// __launch_bounds__(512, 1): R1 (no bound) and R2 (bound=2) both capped the
// allocator at 128 VGPR and spilled the 192-VGPR weight file (VGPR_Count=128,
// WRITE_SIZE +40MB of spill stores, 2.2ms). arg=1 gives a 256-VGPR cap under
// either interpretation of the 2nd arg (1 wave/EU, or 1 block/CU = 2 w/SIMD).
// Hand count: 192 wf + 24 acc + ~25 misc = ~240 <= 256.
__global__ __launch_bounds__(512, 1) void scan_gru(
    const unsigned short* __restrict__ xg,
    const float* __restrict__ whr, const float* __restrict__ whz, const float* __restrict__ whn,
    const float* __restrict__ bhr, const float* __restrict__ bhz, const float* __restrict__ bhn,
    const float* __restrict__ hidden,
    float* __restrict__ outputs, float* __restrict__ hlast) {
    int b = blockIdx.x;
    int tid = threadIdx.x, w = tid >> 6, lane = tid & 63;
    int l15 = lane & 15, grp = lane >> 4;
    __shared__ __align__(16) unsigned short hb[2][Hh];  // double-buffered h (bf16)

    // B-fragments for 3 matrices, 2 col-tiles (wave owns cols [32w, 32w+32)), 8 K-chunks
    u16x8 wf[3][2][8];
    const float* Ws[3] = {whr, whz, whn};
#pragma unroll
    for (int m = 0; m < 3; m++)
#pragma unroll
        for (int ct = 0; ct < 2; ct++) {
            int col = w * 32 + ct * 16 + l15;
#pragma unroll
            for (int kc = 0; kc < 8; kc++) {
                const float* s = Ws[m] + (size_t)col * Hh + kc * 32 + grp * 8;
                float4 f0 = *(const float4*)s, f1 = *(const float4*)(s + 4);
                wf[m][ct][kc] = pack8(f0, f1);
            }
        }

    int col0 = w * 32 + l15, col1 = col0 + 16;
    float bh0r = 0, bh0z = 0, bh0n = 0, bh1r = 0, bh1z = 0, bh1n = 0;
    float hp0 = 0.f, hp1 = 0.f;
    if (lane < 16) {
        bh0r = bhr[col0]; bh0z = bhz[col0]; bh0n = bhn[col0];
        bh1r = bhr[col1]; bh1z = bhz[col1]; bh1n = bhn[col1];
        hp0 = hidden[b * Hh + col0];
        hp1 = hidden[b * Hh + col1];
        hb[0][col0] = f2bf(hp0);
        hb[0][col1] = f2bf(hp1);
        // outputs[:,0,:] = h0 (exact f32)
        outputs[((size_t)b * Tt) * Hh + col0] = hp0;
        outputs[((size_t)b * Tt) * Hh + col1] = hp1;
    }
    const unsigned short* xr = xg;
    const unsigned short* xz = xg + 16777216;
    const unsigned short* xn = xg + 33554432;
    unsigned short nx0 = 0, nx1 = 0, nx2 = 0, nx3 = 0, nx4 = 0, nx5 = 0;
    if (lane < 16) {
        size_t off = ((size_t)1 * 64 + b) * Hh;
        nx0 = xr[off + col0]; nx1 = xr[off + col1];
        nx2 = xz[off + col0]; nx3 = xz[off + col1];
        nx4 = xn[off + col0]; nx5 = xn[off + col1];
    }
    __syncthreads();

    int p = 0;
    for (int t = 1; t < Tt; t++) {
        unsigned short cx0 = nx0, cx1 = nx1, cx2 = nx2, cx3 = nx3, cx4 = nx4, cx5 = nx5;
        int tnext = (t + 1 < Tt) ? t + 1 : t;
        if (lane < 16) {  // prefetch next step's x-projections (latency hidden by MFMA)
            size_t off = ((size_t)tnext * 64 + b) * Hh;
            nx0 = xr[off + col0]; nx1 = xr[off + col1];
            nx2 = xz[off + col0]; nx3 = xz[off + col1];
            nx4 = xn[off + col0]; nx5 = xn[off + col1];
        }
        f32x4 acc[3][2] = {};
#pragma unroll
        for (int kc = 0; kc < 8; kc++) {
            u16x8 af = *(const u16x8*)&hb[p][kc * 32 + grp * 8];  // broadcast read
#pragma unroll
            for (int m = 0; m < 3; m++)
#pragma unroll
                for (int ct = 0; ct < 2; ct++)
                    acc[m][ct] = mfma16(af, wf[m][ct][kc], acc[m][ct]);
        }
        if (lane < 16) {
            float r0 = sigm(bf2f(cx0) + acc[0][0][0] + bh0r);
            float r1 = sigm(bf2f(cx1) + acc[0][1][0] + bh1r);
            float n0 = tanh_f(bf2f(cx4) + r0 * (acc[2][0][0] + bh0n));
            float n1 = tanh_f(bf2f(cx5) + r1 * (acc[2][1][0] + bh1n));
            float z0 = sigm(bf2f(cx2) + acc[1][0][0] + bh0z);
            float z1 = sigm(bf2f(cx3) + acc[1][1][0] + bh1z);
            float hn0 = (1.f - z0) * n0 + z0 * hp0;
            float hn1 = (1.f - z1) * n1 + z1 * hp1;
            hb[p ^ 1][col0] = f2bf(hn0);   // write the OTHER buffer: no read-WAR
            hb[p ^ 1][col1] = f2bf(hn1);
            size_t ro = ((size_t)b * Tt + t) * Hh;
            outputs[ro + col0] = hn0;      // fire-and-forget (no vmcnt drain below)
            outputs[ro + col1] = hn1;
            hp0 = hn0;
            hp1 = hn1;
        }
        p ^= 1;
        // LDS-only barrier: do NOT drain vmcnt (stores + prefetch stay in flight).
        asm volatile("s_waitcnt lgkmcnt(0)" ::: "memory");
        __builtin_amdgcn_s_barrier();
        asm volatile("" ::: "memory");
    }
    if (lane < 16) {
        hlast[b * Hh + col0] = hp0;
        hlast[b * Hh + col1] = hp1;
    }
}

// ---------- launch ----------
extern "C" void kernel_launch(void* const* d_in, const int* in_sizes, int n_in,
                              void* d_out, int out_size, void* d_ws, size_t ws_size,
                              hipStream_t stream) {
    const float* inputs = (const float*)d_in[0];
    const float* hidden = (const float*)d_in[1];
    const float* W_w  = (const float*)d_in[2];
    const float* W_b  = (const float*)d_in[3];
    const float* V_w  = (const float*)d_in[4];
    const float* V_b  = (const float*)d_in[5];
    const float* w_ir = (const float*)d_in[6];
    const float* w_iz = (const float*)d_in[7];
    const float* w_in = (const float*)d_in[8];
    const float* b_ir = (const float*)d_in[9];
    const float* b_iz = (const float*)d_in[10];
    const float* b_in = (const float*)d_in[11];
    const float* w_hr = (const float*)d_in[12];
    const float* w_hz = (const float*)d_in[13];
    const float* w_hn = (const float*)d_in[14];
    const float* b_hr = (const float*)d_in[15];
    const float* b_hz = (const float*)d_in[16];
    const float* b_hn = (const float*)d_in[17];

    // workspace layout (~135.5 MB)
    float* hp = (float*)d_ws;                                  // 65536 f32
    float* partMS = hp + 65536;                                // 64*8*256*2 f32
    unsigned short* zbuf = (unsigned short*)(partMS + 262144); // 16.7M bf16
    unsigned short* ctx = zbuf;                                // alias: z dead after GEMM2
    unsigned short* xgb = zbuf + 16777216;                     // 3 x 16.7M bf16

    float* scores  = (float*)d_out;         // scores staged in outputs slot (dead before scan)
    float* outputs = (float*)d_out;
    float* hlast   = outputs + 16777216;
    float* x_attn  = hlast + 16384;

    hp_kernel<<<64, 256, 0, stream>>>(hidden, W_w, hp);

    gemm_k<0, false><<<dim3(512, 4), 512, 0, stream>>>(
        inputs, W_w, nullptr, nullptr, 512, 256,
        nullptr, nullptr, nullptr, hp, W_b, zbuf);

    gemm_k<1, true><<<dim3(512, 4), 512, 0, stream>>>(
        zbuf, V_w, nullptr, nullptr, 256, 0,
        V_b, nullptr, nullptr, nullptr, nullptr, scores);

    softmax_pass1<<<dim3(64, 8), 256, 0, stream>>>(scores, partMS);
    softmax_pass2<<<dim3(64, 8), 256, 0, stream>>>(scores, partMS, ctx, x_attn);

    gemm_k<2, true><<<dim3(512, 12), 512, 0, stream>>>(
        ctx, w_ir, w_iz, w_in, 256, 0,
        b_ir, b_iz, b_in, nullptr, nullptr, xgb);

    scan_gru<<<64, 512, 0, stream>>>(
        xgb, w_hr, w_hz, w_hn, b_hr, b_hz, b_hn, hidden, outputs, hlast);
}

// Round 4
// 2084.089 us; speedup vs baseline: 1.2897x; 1.2897x over previous
//
#include <hip/hip_runtime.h>

#define DEVI __device__ __forceinline__

typedef float  f32x4  __attribute__((ext_vector_type(4)));
typedef __bf16 bf16x8 __attribute__((ext_vector_type(8)));
typedef unsigned short u16x8 __attribute__((ext_vector_type(8)));

// ---------- helpers ----------
DEVI unsigned short f2bf(float f) {
    unsigned u = __builtin_bit_cast(unsigned, f);
    unsigned r = (u + 0x7fffu + ((u >> 16) & 1u)) >> 16;
    return (unsigned short)r;
}
DEVI float bf2f(unsigned short s) {
    return __builtin_bit_cast(float, (unsigned)s << 16);
}
DEVI u16x8 pack8(float4 a, float4 b) {
    u16x8 p;
    p[0] = f2bf(a.x); p[1] = f2bf(a.y); p[2] = f2bf(a.z); p[3] = f2bf(a.w);
    p[4] = f2bf(b.x); p[5] = f2bf(b.y); p[6] = f2bf(b.z); p[7] = f2bf(b.w);
    return p;
}
DEVI f32x4 mfma16(u16x8 a, u16x8 b, f32x4 c) {
    return __builtin_amdgcn_mfma_f32_16x16x32_bf16(
        __builtin_bit_cast(bf16x8, a), __builtin_bit_cast(bf16x8, b), c, 0, 0, 0);
}
DEVI float sigm(float x)   { return 1.f / (1.f + __expf(-x)); }
DEVI float tanh_f(float x) { return 1.f - 2.f / (1.f + __expf(2.f * x)); }

// dims
#define Hh 256
#define Bb 64
#define Tt 1024
#define MROWS (Bb * Tt)   // 65536

// ---------- K0: hp[b][k] = sum_h hidden[b][h] * W_w[k][h] (first H cols) ----------
__global__ __launch_bounds__(256) void hp_kernel(const float* __restrict__ hid,
                                                 const float* __restrict__ Ww,
                                                 float* __restrict__ hp) {
    int b = blockIdx.x, k = threadIdx.x;
    __shared__ __align__(16) float hs[Hh];
    hs[k] = hid[b * Hh + k];
    __syncthreads();
    const float4* w4 = (const float4*)(Ww + (size_t)k * 512);
    const float4* h4 = (const float4*)hs;
    float acc = 0.f;
#pragma unroll 8
    for (int i = 0; i < 64; i++) {
        float4 a = w4[i], x = h4[i];
        acc += a.x * x.x + a.y * x.y + a.z * x.z + a.w * x.w;
    }
    hp[b * Hh + k] = acc;
}

// ---------- bias prep: cb[0][k]=b_ir+b_hr, cb[1][k]=b_iz+b_hz ----------
__global__ __launch_bounds__(256) void bias_prep(const float* __restrict__ b_ir,
                                                 const float* __restrict__ b_hr,
                                                 const float* __restrict__ b_iz,
                                                 const float* __restrict__ b_hz,
                                                 float* __restrict__ cb) {
    int k = threadIdx.x;
    cb[k] = b_ir[k] + b_hr[k];
    cb[256 + k] = b_iz[k] + b_hz[k];
}

// ---------- GEMM: OUT = epilogue( A(65536x256) @ W^T )  BM=128 BN=64 K=256 ----------
// EPI 0: z = tanh(acc + hp[b][c] + W_b[c]) -> bf16 [r][c]
// EPI 1: scores = acc + V_b[c]            -> f32  [r][c]
// EPI 2: xproj  = acc + b_i[c]            -> bf16 [mat][t][b][c]
template <int EPI, bool ABF16>
__global__ __launch_bounds__(512) void gemm_k(
    const void* __restrict__ Aab,
    const float* __restrict__ W0, const float* __restrict__ W1, const float* __restrict__ W2,
    int wstride, int wcoloff,
    const float* __restrict__ bv0, const float* __restrict__ bv1, const float* __restrict__ bv2,
    const float* __restrict__ hp, const float* __restrict__ Wb,
    void* __restrict__ outv) {
    __shared__ __align__(16) unsigned short As[128 * 256];
    __shared__ __align__(16) unsigned short Bs[64 * 256];

    int tid = threadIdx.x;
    int bx = blockIdx.x, by = blockIdx.y;
    int mat = (EPI == 2) ? (by >> 2) : 0;
    int cb  = (EPI == 2) ? (by & 3) : by;
    int rowBase = bx * 128, colBase = cb * 64;
    const float* W  = (mat == 0) ? W0 : ((mat == 1) ? W1 : W2);
    const float* bv = (mat == 0) ? bv0 : ((mat == 1) ? bv1 : bv2);

    // stage A: 128 rows x 32 chunks(16B), swizzled g ^= (r&7)
    if (ABF16) {
        const unsigned short* A = (const unsigned short*)Aab;
#pragma unroll
        for (int i = 0; i < 8; i++) {
            int idx = i * 512 + tid, r = idx >> 5, g = idx & 31, gs = g ^ (r & 7);
            *(uint4*)&As[r * 256 + gs * 8] =
                *(const uint4*)(A + (((size_t)(rowBase + r)) << 8) + g * 8);
        }
    } else {
        const float* A = (const float*)Aab;
#pragma unroll
        for (int i = 0; i < 8; i++) {
            int idx = i * 512 + tid, r = idx >> 5, g = idx & 31, gs = g ^ (r & 7);
            const float* s = A + (((size_t)(rowBase + r)) << 8) + g * 8;
            float4 f0 = *(const float4*)s, f1 = *(const float4*)(s + 4);
            *(u16x8*)&As[r * 256 + gs * 8] = pack8(f0, f1);
        }
    }
    // stage B: 64 W-rows (output cols) x 32 chunks
#pragma unroll
    for (int i = 0; i < 4; i++) {
        int idx = i * 512 + tid, r = idx >> 5, g = idx & 31, gs = g ^ (r & 7);
        const float* s = W + (size_t)(colBase + r) * wstride + wcoloff + g * 8;
        float4 f0 = *(const float4*)s, f1 = *(const float4*)(s + 4);
        *(u16x8*)&Bs[r * 256 + gs * 8] = pack8(f0, f1);
    }
    __syncthreads();

    int wid = tid >> 6, lane = tid & 63, l15 = lane & 15, grp = lane >> 4;
    int wr = (wid >> 1) * 32, wc = (wid & 1) * 32;
    f32x4 acc[2][2] = {};
#pragma unroll
    for (int kc = 0; kc < 8; kc++) {
        u16x8 a[2], bb[2];
#pragma unroll
        for (int rt = 0; rt < 2; rt++) {
            int r = wr + rt * 16 + l15;
            int gs = (kc * 4 + grp) ^ (r & 7);
            a[rt] = *(const u16x8*)&As[r * 256 + gs * 8];
        }
#pragma unroll
        for (int ct = 0; ct < 2; ct++) {
            int r = wc + ct * 16 + l15;
            int gs = (kc * 4 + grp) ^ (r & 7);
            bb[ct] = *(const u16x8*)&Bs[r * 256 + gs * 8];
        }
#pragma unroll
        for (int rt = 0; rt < 2; rt++)
#pragma unroll
            for (int ct = 0; ct < 2; ct++)
                acc[rt][ct] = mfma16(a[rt], bb[ct], acc[rt][ct]);
    }
    // epilogue: D row = (lane>>4)*4 + i, col = lane&15
#pragma unroll
    for (int rt = 0; rt < 2; rt++)
#pragma unroll
        for (int ct = 0; ct < 2; ct++)
#pragma unroll
            for (int i = 0; i < 4; i++) {
                int rl = wr + rt * 16 + grp * 4 + i;
                int cl = wc + ct * 16 + l15;
                size_t r = (size_t)rowBase + rl;
                int c = colBase + cl;
                float v = acc[rt][ct][i];
                if (EPI == 0) {
                    v = tanh_f(v + hp[(r >> 10) * 256 + c] + Wb[c]);
                    ((unsigned short*)outv)[r * 256 + c] = f2bf(v);
                } else if (EPI == 1) {
                    ((float*)outv)[r * 256 + c] = v + bv[c];
                } else {
                    size_t t = r & 1023, b = r >> 10;
                    ((unsigned short*)outv)[(size_t)mat * 16777216 + (t * 64 + b) * 256 + c] =
                        f2bf(v + bv[c]);
                }
            }
}

// ---------- softmax over T, pass 1: per (b,k) online max/sumexp over a T-chunk ----------
__global__ __launch_bounds__(256) void softmax_pass1(const float* __restrict__ scores,
                                                     float* __restrict__ partMS) {
    int b = blockIdx.x, tc = blockIdx.y, k = threadIdx.x;
    const float* p = scores + ((size_t)b * Tt + tc * 128) * Hh + k;
    float m = -1e30f, S = 0.f;
    for (int i = 0; i < 128; i++) {
        float s = p[(size_t)i * Hh];
        float mn = fmaxf(m, s);
        S = S * __expf(m - mn) + __expf(s - mn);
        m = mn;
    }
    int idx = (b * 8 + tc) * Hh + k;
    partMS[idx * 2] = m;
    partMS[idx * 2 + 1] = S;
}

// ---------- softmax pass 2: combine partials, emit ctx (bf16) and x_attn ----------
__global__ __launch_bounds__(256) void softmax_pass2(const float* __restrict__ scores,
                                                     const float* __restrict__ partMS,
                                                     unsigned short* __restrict__ ctx,
                                                     float* __restrict__ x_attn) {
    int b = blockIdx.x, tc = blockIdx.y;
    int tid = threadIdx.x, w = tid >> 6, lane = tid & 63;
    float mj[4], Sj[4];
#pragma unroll
    for (int j = 0; j < 4; j++) {
        int k = lane + j * 64;
        float m = -1e30f;
#pragma unroll
        for (int c = 0; c < 8; c++)
            m = fmaxf(m, partMS[((b * 8 + c) * Hh + k) * 2]);
        float S = 0.f;
#pragma unroll
        for (int c = 0; c < 8; c++) {
            int idx = (b * 8 + c) * Hh + k;
            S += partMS[idx * 2 + 1] * __expf(partMS[idx * 2] - m);
        }
        mj[j] = m;
        Sj[j] = 1.f / S;
    }
    for (int i = 0; i < 32; i++) {
        int t = tc * 128 + w * 32 + i;
        const float* sp = scores + ((size_t)b * Tt + t) * Hh;
        unsigned short* cp = ctx + ((size_t)b * Tt + t) * Hh;
        float accsm = 0.f;
#pragma unroll
        for (int j = 0; j < 4; j++) {
            int k = lane + j * 64;
            float s = sp[k];
            float sm = __expf(s - mj[j]) * Sj[j];
            accsm += sm;
            cp[k] = f2bf(s * sm);
        }
#pragma unroll
        for (int o = 32; o >= 1; o >>= 1) accsm += __shfl_xor(accsm, o, 64);
        if (lane == 0) x_attn[b * Tt + t] = accsm;
    }
}

// ---------- GRU scan: one block per batch row, weights in registers ----------
// R1-R3: 512-thread version needed 192 weight VGPRs/lane; allocator capped at
// 128 under every launch_bounds variant -> full spill (2.4ms, MfmaUtil 7%).
// Fix: 1024 threads / 16 waves; wave w owns cols [16w,16w+16) for ALL THREE
// matrices -> 24 B-frags = 96 VGPRs + 12 acc + ~20 misc, fits the 128 cap.
// b_hr/b_hz folded into the EPI2 bias (bias_prep); b_hn stays (inside r*(...)).
__global__ __launch_bounds__(1024) void scan_gru(
    const unsigned short* __restrict__ xg,
    const float* __restrict__ whr, const float* __restrict__ whz, const float* __restrict__ whn,
    const float* __restrict__ bhn,
    const float* __restrict__ hidden,
    float* __restrict__ outputs, float* __restrict__ hlast) {
    int b = blockIdx.x;
    int tid = threadIdx.x, w = tid >> 6, lane = tid & 63;
    int l15 = lane & 15, grp = lane >> 4;
    __shared__ __align__(16) unsigned short hb[2][Hh];  // double-buffered h (bf16)

    int col = w * 16 + l15;  // this wave's 16 output columns
    u16x8 wf[3][8];
    const float* Ws[3] = {whr, whz, whn};
#pragma unroll
    for (int m = 0; m < 3; m++)
#pragma unroll
        for (int kc = 0; kc < 8; kc++) {
            const float* s = Ws[m] + (size_t)col * Hh + kc * 32 + grp * 8;
            float4 f0 = *(const float4*)s, f1 = *(const float4*)(s + 4);
            wf[m][kc] = pack8(f0, f1);
        }

    float bhn0 = 0.f, hp0 = 0.f;
    if (lane < 16) {
        bhn0 = bhn[col];
        hp0 = hidden[b * Hh + col];
        hb[0][col] = f2bf(hp0);
        outputs[((size_t)b * Tt) * Hh + col] = hp0;  // outputs[:,0,:] = h0 exact
    }
    const unsigned short* xr = xg;
    const unsigned short* xz = xg + 16777216;
    const unsigned short* xn = xg + 33554432;
    unsigned short nx0 = 0, nx1 = 0, nx2 = 0;
    if (lane < 16) {
        size_t off = ((size_t)64 + b) * Hh + col;  // t=1
        nx0 = xr[off]; nx1 = xz[off]; nx2 = xn[off];
    }
    __syncthreads();

    int p = 0;
    for (int t = 1; t < Tt; t++) {
        unsigned short cx0 = nx0, cx1 = nx1, cx2 = nx2;
        int tnext = (t + 1 < Tt) ? t + 1 : t;
        if (lane < 16) {  // prefetch next step (latency hidden under MFMAs)
            size_t off = ((size_t)tnext * 64 + b) * Hh + col;
            nx0 = xr[off]; nx1 = xz[off]; nx2 = xn[off];
        }
        f32x4 acc[3] = {};
#pragma unroll
        for (int kc = 0; kc < 8; kc++) {
            u16x8 af = *(const u16x8*)&hb[p][kc * 32 + grp * 8];  // broadcast read
#pragma unroll
            for (int m = 0; m < 3; m++)
                acc[m] = mfma16(af, wf[m][kc], acc[m]);
        }
        if (lane < 16) {
            float r0 = sigm(bf2f(cx0) + acc[0][0]);          // b_ir+b_hr pre-folded
            float z0 = sigm(bf2f(cx1) + acc[1][0]);          // b_iz+b_hz pre-folded
            float n0 = tanh_f(bf2f(cx2) + r0 * (acc[2][0] + bhn0));
            float hn0 = (1.f - z0) * n0 + z0 * hp0;
            hb[p ^ 1][col] = f2bf(hn0);   // write the OTHER buffer: no read-WAR
            outputs[((size_t)b * Tt + t) * Hh + col] = hn0;  // fire-and-forget
            hp0 = hn0;
        }
        p ^= 1;
        // LDS-only barrier: do NOT drain vmcnt (stores + prefetch stay in flight).
        asm volatile("s_waitcnt lgkmcnt(0)" ::: "memory");
        __builtin_amdgcn_s_barrier();
        asm volatile("" ::: "memory");
    }
    if (lane < 16) {
        hlast[b * Hh + col] = hp0;
    }
}

// ---------- launch ----------
extern "C" void kernel_launch(void* const* d_in, const int* in_sizes, int n_in,
                              void* d_out, int out_size, void* d_ws, size_t ws_size,
                              hipStream_t stream) {
    const float* inputs = (const float*)d_in[0];
    const float* hidden = (const float*)d_in[1];
    const float* W_w  = (const float*)d_in[2];
    const float* W_b  = (const float*)d_in[3];
    const float* V_w  = (const float*)d_in[4];
    const float* V_b  = (const float*)d_in[5];
    const float* w_ir = (const float*)d_in[6];
    const float* w_iz = (const float*)d_in[7];
    const float* w_in = (const float*)d_in[8];
    const float* b_ir = (const float*)d_in[9];
    const float* b_iz = (const float*)d_in[10];
    const float* b_in = (const float*)d_in[11];
    const float* w_hr = (const float*)d_in[12];
    const float* w_hz = (const float*)d_in[13];
    const float* w_hn = (const float*)d_in[14];
    const float* b_hr = (const float*)d_in[15];
    const float* b_hz = (const float*)d_in[16];
    const float* b_hn = (const float*)d_in[17];

    // workspace layout (~135.5 MB)
    float* hp = (float*)d_ws;                                  // 65536 f32
    float* partMS = hp + 65536;                                // 64*8*256*2 f32
    float* cbias = partMS + 262144;                            // 512 f32
    unsigned short* zbuf = (unsigned short*)(cbias + 512);     // 16.7M bf16
    unsigned short* ctx = zbuf;                                // alias: z dead after GEMM2
    unsigned short* xgb = zbuf + 16777216;                     // 3 x 16.7M bf16

    float* scores  = (float*)d_out;         // scores staged in outputs slot (dead before scan)
    float* outputs = (float*)d_out;
    float* hlast   = outputs + 16777216;
    float* x_attn  = hlast + 16384;

    hp_kernel<<<64, 256, 0, stream>>>(hidden, W_w, hp);
    bias_prep<<<1, 256, 0, stream>>>(b_ir, b_hr, b_iz, b_hz, cbias);

    gemm_k<0, false><<<dim3(512, 4), 512, 0, stream>>>(
        inputs, W_w, nullptr, nullptr, 512, 256,
        nullptr, nullptr, nullptr, hp, W_b, zbuf);

    gemm_k<1, true><<<dim3(512, 4), 512, 0, stream>>>(
        zbuf, V_w, nullptr, nullptr, 256, 0,
        V_b, nullptr, nullptr, nullptr, nullptr, scores);

    softmax_pass1<<<dim3(64, 8), 256, 0, stream>>>(scores, partMS);
    softmax_pass2<<<dim3(64, 8), 256, 0, stream>>>(scores, partMS, ctx, x_attn);

    gemm_k<2, true><<<dim3(512, 12), 512, 0, stream>>>(
        ctx, w_ir, w_iz, w_in, 256, 0,
        cbias, cbias + 256, b_in, nullptr, nullptr, xgb);

    scan_gru<<<64, 1024, 0, stream>>>(
        xgb, w_hr, w_hz, w_hn, b_hn, hidden, outputs, hlast);
}

// Round 5
// 1704.626 us; speedup vs baseline: 1.5768x; 1.2226x over previous
//
#include <hip/hip_runtime.h>

#define DEVI __device__ __forceinline__

typedef float  f32x4  __attribute__((ext_vector_type(4)));
typedef __bf16 bf16x8 __attribute__((ext_vector_type(8)));
typedef unsigned short u16x8 __attribute__((ext_vector_type(8)));

// ---------- helpers ----------
DEVI unsigned short f2bf(float f) {
    unsigned u = __builtin_bit_cast(unsigned, f);
    unsigned r = (u + 0x7fffu + ((u >> 16) & 1u)) >> 16;
    return (unsigned short)r;
}
DEVI float bf2f(unsigned short s) {
    return __builtin_bit_cast(float, (unsigned)s << 16);
}
DEVI u16x8 pack8(float4 a, float4 b) {
    u16x8 p;
    p[0] = f2bf(a.x); p[1] = f2bf(a.y); p[2] = f2bf(a.z); p[3] = f2bf(a.w);
    p[4] = f2bf(b.x); p[5] = f2bf(b.y); p[6] = f2bf(b.z); p[7] = f2bf(b.w);
    return p;
}
DEVI f32x4 mfma16(u16x8 a, u16x8 b, f32x4 c) {
    return __builtin_amdgcn_mfma_f32_16x16x32_bf16(
        __builtin_bit_cast(bf16x8, a), __builtin_bit_cast(bf16x8, b), c, 0, 0, 0);
}
DEVI float sigm(float x)   { return 1.f / (1.f + __expf(-x)); }
DEVI float tanh_f(float x) { return 1.f - 2.f / (1.f + __expf(2.f * x)); }

// dims
#define Hh 256
#define Bb 64
#define Tt 1024
#define MROWS (Bb * Tt)   // 65536

// ---------- K0: hp[b][k] = sum_h hidden[b][h] * W_w[k][h] (first H cols) ----------
__global__ __launch_bounds__(256) void hp_kernel(const float* __restrict__ hid,
                                                 const float* __restrict__ Ww,
                                                 float* __restrict__ hp) {
    int b = blockIdx.x, k = threadIdx.x;
    __shared__ __align__(16) float hs[Hh];
    hs[k] = hid[b * Hh + k];
    __syncthreads();
    const float4* w4 = (const float4*)(Ww + (size_t)k * 512);
    const float4* h4 = (const float4*)hs;
    float acc = 0.f;
#pragma unroll 8
    for (int i = 0; i < 64; i++) {
        float4 a = w4[i], x = h4[i];
        acc += a.x * x.x + a.y * x.y + a.z * x.z + a.w * x.w;
    }
    hp[b * Hh + k] = acc;
}

// ---------- bias prep: cb[0][k]=b_ir+b_hr, cb[1][k]=b_iz+b_hz ----------
__global__ __launch_bounds__(256) void bias_prep(const float* __restrict__ b_ir,
                                                 const float* __restrict__ b_hr,
                                                 const float* __restrict__ b_iz,
                                                 const float* __restrict__ b_hz,
                                                 float* __restrict__ cb) {
    int k = threadIdx.x;
    cb[k] = b_ir[k] + b_hr[k];
    cb[256 + k] = b_iz[k] + b_hz[k];
}

// ---------- GEMM: OUT = epilogue( A(65536x256) @ W^T )  BM=128 BN=64 K=256 ----------
// EPI 0: z = tanh(acc + hp[b][c] + W_b[c]) -> bf16 [r][c]
// EPI 1: scores = acc + V_b[c]            -> f32  [r][c]
// EPI 2: xproj  = acc + b_i[c]            -> bf16 [mat][t][b][c]
template <int EPI, bool ABF16>
__global__ __launch_bounds__(512) void gemm_k(
    const void* __restrict__ Aab,
    const float* __restrict__ W0, const float* __restrict__ W1, const float* __restrict__ W2,
    int wstride, int wcoloff,
    const float* __restrict__ bv0, const float* __restrict__ bv1, const float* __restrict__ bv2,
    const float* __restrict__ hp, const float* __restrict__ Wb,
    void* __restrict__ outv) {
    __shared__ __align__(16) unsigned short As[128 * 256];
    __shared__ __align__(16) unsigned short Bs[64 * 256];

    int tid = threadIdx.x;
    int bx = blockIdx.x, by = blockIdx.y;
    int mat = (EPI == 2) ? (by >> 2) : 0;
    int cb  = (EPI == 2) ? (by & 3) : by;
    int rowBase = bx * 128, colBase = cb * 64;
    const float* W  = (mat == 0) ? W0 : ((mat == 1) ? W1 : W2);
    const float* bv = (mat == 0) ? bv0 : ((mat == 1) ? bv1 : bv2);

    // stage A: 128 rows x 32 chunks(16B), swizzled g ^= (r&7)
    if (ABF16) {
        const unsigned short* A = (const unsigned short*)Aab;
#pragma unroll
        for (int i = 0; i < 8; i++) {
            int idx = i * 512 + tid, r = idx >> 5, g = idx & 31, gs = g ^ (r & 7);
            *(uint4*)&As[r * 256 + gs * 8] =
                *(const uint4*)(A + (((size_t)(rowBase + r)) << 8) + g * 8);
        }
    } else {
        const float* A = (const float*)Aab;
#pragma unroll
        for (int i = 0; i < 8; i++) {
            int idx = i * 512 + tid, r = idx >> 5, g = idx & 31, gs = g ^ (r & 7);
            const float* s = A + (((size_t)(rowBase + r)) << 8) + g * 8;
            float4 f0 = *(const float4*)s, f1 = *(const float4*)(s + 4);
            *(u16x8*)&As[r * 256 + gs * 8] = pack8(f0, f1);
        }
    }
    // stage B: 64 W-rows (output cols) x 32 chunks
#pragma unroll
    for (int i = 0; i < 4; i++) {
        int idx = i * 512 + tid, r = idx >> 5, g = idx & 31, gs = g ^ (r & 7);
        const float* s = W + (size_t)(colBase + r) * wstride + wcoloff + g * 8;
        float4 f0 = *(const float4*)s, f1 = *(const float4*)(s + 4);
        *(u16x8*)&Bs[r * 256 + gs * 8] = pack8(f0, f1);
    }
    __syncthreads();

    int wid = tid >> 6, lane = tid & 63, l15 = lane & 15, grp = lane >> 4;
    int wr = (wid >> 1) * 32, wc = (wid & 1) * 32;
    f32x4 acc[2][2] = {};
#pragma unroll
    for (int kc = 0; kc < 8; kc++) {
        u16x8 a[2], bb[2];
#pragma unroll
        for (int rt = 0; rt < 2; rt++) {
            int r = wr + rt * 16 + l15;
            int gs = (kc * 4 + grp) ^ (r & 7);
            a[rt] = *(const u16x8*)&As[r * 256 + gs * 8];
        }
#pragma unroll
        for (int ct = 0; ct < 2; ct++) {
            int r = wc + ct * 16 + l15;
            int gs = (kc * 4 + grp) ^ (r & 7);
            bb[ct] = *(const u16x8*)&Bs[r * 256 + gs * 8];
        }
#pragma unroll
        for (int rt = 0; rt < 2; rt++)
#pragma unroll
            for (int ct = 0; ct < 2; ct++)
                acc[rt][ct] = mfma16(a[rt], bb[ct], acc[rt][ct]);
    }
    // epilogue: D row = (lane>>4)*4 + i, col = lane&15
#pragma unroll
    for (int rt = 0; rt < 2; rt++)
#pragma unroll
        for (int ct = 0; ct < 2; ct++)
#pragma unroll
            for (int i = 0; i < 4; i++) {
                int rl = wr + rt * 16 + grp * 4 + i;
                int cl = wc + ct * 16 + l15;
                size_t r = (size_t)rowBase + rl;
                int c = colBase + cl;
                float v = acc[rt][ct][i];
                if (EPI == 0) {
                    v = tanh_f(v + hp[(r >> 10) * 256 + c] + Wb[c]);
                    ((unsigned short*)outv)[r * 256 + c] = f2bf(v);
                } else if (EPI == 1) {
                    ((float*)outv)[r * 256 + c] = v + bv[c];
                } else {
                    size_t t = r & 1023, b = r >> 10;
                    ((unsigned short*)outv)[(size_t)mat * 16777216 + (t * 64 + b) * 256 + c] =
                        f2bf(v + bv[c]);
                }
            }
}

// ---------- softmax over T, pass 1: per (b,k) online max/sumexp over a T-chunk ----------
__global__ __launch_bounds__(256) void softmax_pass1(const float* __restrict__ scores,
                                                     float* __restrict__ partMS) {
    int b = blockIdx.x, tc = blockIdx.y, k = threadIdx.x;
    const float* p = scores + ((size_t)b * Tt + tc * 128) * Hh + k;
    float m = -1e30f, S = 0.f;
    for (int i = 0; i < 128; i++) {
        float s = p[(size_t)i * Hh];
        float mn = fmaxf(m, s);
        S = S * __expf(m - mn) + __expf(s - mn);
        m = mn;
    }
    int idx = (b * 8 + tc) * Hh + k;
    partMS[idx * 2] = m;
    partMS[idx * 2 + 1] = S;
}

// ---------- softmax pass 2: combine partials, emit ctx (bf16) and x_attn ----------
__global__ __launch_bounds__(256) void softmax_pass2(const float* __restrict__ scores,
                                                     const float* __restrict__ partMS,
                                                     unsigned short* __restrict__ ctx,
                                                     float* __restrict__ x_attn) {
    int b = blockIdx.x, tc = blockIdx.y;
    int tid = threadIdx.x, w = tid >> 6, lane = tid & 63;
    float mj[4], Sj[4];
#pragma unroll
    for (int j = 0; j < 4; j++) {
        int k = lane + j * 64;
        float m = -1e30f;
#pragma unroll
        for (int c = 0; c < 8; c++)
            m = fmaxf(m, partMS[((b * 8 + c) * Hh + k) * 2]);
        float S = 0.f;
#pragma unroll
        for (int c = 0; c < 8; c++) {
            int idx = (b * 8 + c) * Hh + k;
            S += partMS[idx * 2 + 1] * __expf(partMS[idx * 2] - m);
        }
        mj[j] = m;
        Sj[j] = 1.f / S;
    }
    for (int i = 0; i < 32; i++) {
        int t = tc * 128 + w * 32 + i;
        const float* sp = scores + ((size_t)b * Tt + t) * Hh;
        unsigned short* cp = ctx + ((size_t)b * Tt + t) * Hh;
        float accsm = 0.f;
#pragma unroll
        for (int j = 0; j < 4; j++) {
            int k = lane + j * 64;
            float s = sp[k];
            float sm = __expf(s - mj[j]) * Sj[j];
            accsm += sm;
            cp[k] = f2bf(s * sm);
        }
#pragma unroll
        for (int o = 32; o >= 1; o >>= 1) accsm += __shfl_xor(accsm, o, 64);
        if (lane == 0) x_attn[b * Tt + t] = accsm;
    }
}

// ---------- GRU scan: one block per batch row, weights in registers ----------
// R1-R4 post-mortem: the allocator ALWAYS budgets for 2 workgroups/CU
// (512thr->128 VGPR, 1024thr->64 VGPR) and ignores launch_bounds' min-waves
// hint, so the weight file spilled every round. Fix: 112 KB static LDS makes
// a 2nd workgroup physically impossible (160 KB/CU), forcing the occupancy
// calc to 1 WG/CU = 2 waves/EU -> 256-VGPR budget. Need: 192 wf + 24 acc
// + ~20 misc = ~240. Also use raw backend attrs instead of launch_bounds.
#define HBPAD 28672  // u16 elems per buffer; 2*28672*2B = 112 KB LDS
__global__ __attribute__((amdgpu_flat_work_group_size(512, 512),
                          amdgpu_waves_per_eu(2, 2)))
void scan_gru(
    const unsigned short* __restrict__ xg,
    const float* __restrict__ whr, const float* __restrict__ whz, const float* __restrict__ whn,
    const float* __restrict__ bhn,
    const float* __restrict__ hidden,
    float* __restrict__ outputs, float* __restrict__ hlast) {
    int b = blockIdx.x;
    int tid = threadIdx.x, w = tid >> 6, lane = tid & 63;
    int l15 = lane & 15, grp = lane >> 4;
    __shared__ __align__(16) unsigned short hb[2][HBPAD];  // h dbuf in first 256; rest = occupancy limiter

    // B-fragments: wave owns cols [32w,32w+32) for ALL 3 matrices (no cross-wave exchange)
    u16x8 wf[3][2][8];
    const float* Ws[3] = {whr, whz, whn};
#pragma unroll
    for (int m = 0; m < 3; m++)
#pragma unroll
        for (int ct = 0; ct < 2; ct++) {
            int col = w * 32 + ct * 16 + l15;
#pragma unroll
            for (int kc = 0; kc < 8; kc++) {
                const float* s = Ws[m] + (size_t)col * Hh + kc * 32 + grp * 8;
                float4 f0 = *(const float4*)s, f1 = *(const float4*)(s + 4);
                wf[m][ct][kc] = pack8(f0, f1);
            }
        }

    int col0 = w * 32 + l15, col1 = col0 + 16;
    float bhn0 = 0.f, bhn1 = 0.f, hp0 = 0.f, hp1 = 0.f;
    if (lane < 16) {
        bhn0 = bhn[col0];
        bhn1 = bhn[col1];
        hp0 = hidden[b * Hh + col0];
        hp1 = hidden[b * Hh + col1];
        hb[0][col0] = f2bf(hp0);
        hb[0][col1] = f2bf(hp1);
        outputs[((size_t)b * Tt) * Hh + col0] = hp0;  // outputs[:,0,:] = h0 exact
        outputs[((size_t)b * Tt) * Hh + col1] = hp1;
    }
    const unsigned short* xr = xg;
    const unsigned short* xz = xg + 16777216;
    const unsigned short* xn = xg + 33554432;
    unsigned short nx0 = 0, nx1 = 0, nx2 = 0, nx3 = 0, nx4 = 0, nx5 = 0;
    if (lane < 16) {
        size_t off = ((size_t)64 + b) * Hh;  // t=1
        nx0 = xr[off + col0]; nx1 = xr[off + col1];
        nx2 = xz[off + col0]; nx3 = xz[off + col1];
        nx4 = xn[off + col0]; nx5 = xn[off + col1];
    }
    __syncthreads();

    int p = 0;
    for (int t = 1; t < Tt; t++) {
        unsigned short cx0 = nx0, cx1 = nx1, cx2 = nx2, cx3 = nx3, cx4 = nx4, cx5 = nx5;
        int tnext = (t + 1 < Tt) ? t + 1 : t;
        if (lane < 16) {  // prefetch next step (latency hidden under MFMAs)
            size_t off = ((size_t)tnext * 64 + b) * Hh;
            nx0 = xr[off + col0]; nx1 = xr[off + col1];
            nx2 = xz[off + col0]; nx3 = xz[off + col1];
            nx4 = xn[off + col0]; nx5 = xn[off + col1];
        }
        f32x4 acc[3][2] = {};
#pragma unroll
        for (int kc = 0; kc < 8; kc++) {
            u16x8 af = *(const u16x8*)&hb[p][kc * 32 + grp * 8];  // broadcast read
#pragma unroll
            for (int m = 0; m < 3; m++)
#pragma unroll
                for (int ct = 0; ct < 2; ct++)
                    acc[m][ct] = mfma16(af, wf[m][ct][kc], acc[m][ct]);
        }
        if (lane < 16) {
            float r0 = sigm(bf2f(cx0) + acc[0][0][0]);   // b_ir+b_hr pre-folded
            float r1 = sigm(bf2f(cx1) + acc[0][1][0]);
            float z0 = sigm(bf2f(cx2) + acc[1][0][0]);   // b_iz+b_hz pre-folded
            float z1 = sigm(bf2f(cx3) + acc[1][1][0]);
            float n0 = tanh_f(bf2f(cx4) + r0 * (acc[2][0][0] + bhn0));
            float n1 = tanh_f(bf2f(cx5) + r1 * (acc[2][1][0] + bhn1));
            float hn0 = (1.f - z0) * n0 + z0 * hp0;
            float hn1 = (1.f - z1) * n1 + z1 * hp1;
            hb[p ^ 1][col0] = f2bf(hn0);   // write the OTHER buffer: no read-WAR
            hb[p ^ 1][col1] = f2bf(hn1);
            size_t ro = ((size_t)b * Tt + t) * Hh;
            outputs[ro + col0] = hn0;      // fire-and-forget (no vmcnt drain below)
            outputs[ro + col1] = hn1;
            hp0 = hn0;
            hp1 = hn1;
        }
        p ^= 1;
        // LDS-only barrier: do NOT drain vmcnt (stores + prefetch stay in flight).
        asm volatile("s_waitcnt lgkmcnt(0)" ::: "memory");
        __builtin_amdgcn_s_barrier();
        asm volatile("" ::: "memory");
    }
    if (lane < 16) {
        hlast[b * Hh + col0] = hp0;
        hlast[b * Hh + col1] = hp1;
    }
}

// ---------- launch ----------
extern "C" void kernel_launch(void* const* d_in, const int* in_sizes, int n_in,
                              void* d_out, int out_size, void* d_ws, size_t ws_size,
                              hipStream_t stream) {
    const float* inputs = (const float*)d_in[0];
    const float* hidden = (const float*)d_in[1];
    const float* W_w  = (const float*)d_in[2];
    const float* W_b  = (const float*)d_in[3];
    const float* V_w  = (const float*)d_in[4];
    const float* V_b  = (const float*)d_in[5];
    const float* w_ir = (const float*)d_in[6];
    const float* w_iz = (const float*)d_in[7];
    const float* w_in = (const float*)d_in[8];
    const float* b_ir = (const float*)d_in[9];
    const float* b_iz = (const float*)d_in[10];
    const float* b_in = (const float*)d_in[11];
    const float* w_hr = (const float*)d_in[12];
    const float* w_hz = (const float*)d_in[13];
    const float* w_hn = (const float*)d_in[14];
    const float* b_hr = (const float*)d_in[15];
    const float* b_hz = (const float*)d_in[16];
    const float* b_hn = (const float*)d_in[17];

    // workspace layout (~135.5 MB)
    float* hp = (float*)d_ws;                                  // 65536 f32
    float* partMS = hp + 65536;                                // 64*8*256*2 f32
    float* cbias = partMS + 262144;                            // 512 f32
    unsigned short* zbuf = (unsigned short*)(cbias + 512);     // 16.7M bf16
    unsigned short* ctx = zbuf;                                // alias: z dead after GEMM2
    unsigned short* xgb = zbuf + 16777216;                     // 3 x 16.7M bf16

    float* scores  = (float*)d_out;         // scores staged in outputs slot (dead before scan)
    float* outputs = (float*)d_out;
    float* hlast   = outputs + 16777216;
    float* x_attn  = hlast + 16384;

    hp_kernel<<<64, 256, 0, stream>>>(hidden, W_w, hp);
    bias_prep<<<1, 256, 0, stream>>>(b_ir, b_hr, b_iz, b_hz, cbias);

    gemm_k<0, false><<<dim3(512, 4), 512, 0, stream>>>(
        inputs, W_w, nullptr, nullptr, 512, 256,
        nullptr, nullptr, nullptr, hp, W_b, zbuf);

    gemm_k<1, true><<<dim3(512, 4), 512, 0, stream>>>(
        zbuf, V_w, nullptr, nullptr, 256, 0,
        V_b, nullptr, nullptr, nullptr, nullptr, scores);

    softmax_pass1<<<dim3(64, 8), 256, 0, stream>>>(scores, partMS);
    softmax_pass2<<<dim3(64, 8), 256, 0, stream>>>(scores, partMS, ctx, x_attn);

    gemm_k<2, true><<<dim3(512, 12), 512, 0, stream>>>(
        ctx, w_ir, w_iz, w_in, 256, 0,
        cbias, cbias + 256, b_in, nullptr, nullptr, xgb);

    scan_gru<<<64, 512, 0, stream>>>(
        xgb, w_hr, w_hz, w_hn, b_hn, hidden, outputs, hlast);
}

// Round 8
// 1637.224 us; speedup vs baseline: 1.6418x; 1.0412x over previous
//
#include <hip/hip_runtime.h>

#define DEVI __device__ __forceinline__

typedef float  f32x4  __attribute__((ext_vector_type(4)));
typedef __bf16 bf16x8 __attribute__((ext_vector_type(8)));
typedef unsigned short u16x8 __attribute__((ext_vector_type(8)));

// ---------- helpers ----------
DEVI unsigned short f2bf(float f) {
    unsigned u = __builtin_bit_cast(unsigned, f);
    unsigned r = (u + 0x7fffu + ((u >> 16) & 1u)) >> 16;
    return (unsigned short)r;
}
DEVI float bf2f(unsigned short s) {
    return __builtin_bit_cast(float, (unsigned)s << 16);
}
DEVI u16x8 pack8(float4 a, float4 b) {
    u16x8 p;
    p[0] = f2bf(a.x); p[1] = f2bf(a.y); p[2] = f2bf(a.z); p[3] = f2bf(a.w);
    p[4] = f2bf(b.x); p[5] = f2bf(b.y); p[6] = f2bf(b.z); p[7] = f2bf(b.w);
    return p;
}
DEVI f32x4 mfma16(u16x8 a, u16x8 b, f32x4 c) {
    return __builtin_amdgcn_mfma_f32_16x16x32_bf16(
        __builtin_bit_cast(bf16x8, a), __builtin_bit_cast(bf16x8, b), c, 0, 0, 0);
}
DEVI float sigm(float x)   { return 1.f / (1.f + __expf(-x)); }
DEVI float tanh_f(float x) { return 1.f - 2.f / (1.f + __expf(2.f * x)); }

// dims
#define Hh 256
#define Bb 64
#define Tt 1024
#define MROWS (Bb * Tt)   // 65536

// ---------- K0: hp[b][k] = sum_h hidden[b][h] * W_w[k][h] (first H cols) ----------
__global__ __launch_bounds__(256) void hp_kernel(const float* __restrict__ hid,
                                                 const float* __restrict__ Ww,
                                                 float* __restrict__ hp) {
    int b = blockIdx.x, k = threadIdx.x;
    __shared__ __align__(16) float hs[Hh];
    hs[k] = hid[b * Hh + k];
    __syncthreads();
    const float4* w4 = (const float4*)(Ww + (size_t)k * 512);
    const float4* h4 = (const float4*)hs;
    float acc = 0.f;
#pragma unroll 8
    for (int i = 0; i < 64; i++) {
        float4 a = w4[i], x = h4[i];
        acc += a.x * x.x + a.y * x.y + a.z * x.z + a.w * x.w;
    }
    hp[b * Hh + k] = acc;
}

// ---------- bias prep: cb[0][k]=b_ir+b_hr, cb[1][k]=b_iz+b_hz ----------
__global__ __launch_bounds__(256) void bias_prep(const float* __restrict__ b_ir,
                                                 const float* __restrict__ b_hr,
                                                 const float* __restrict__ b_iz,
                                                 const float* __restrict__ b_hz,
                                                 float* __restrict__ cb) {
    int k = threadIdx.x;
    cb[k] = b_ir[k] + b_hr[k];
    cb[256 + k] = b_iz[k] + b_hz[k];
}

// ---------- GEMM: OUT = epilogue( A(65536x256) @ W^T )  BM=128 BN=64 K=256 ----------
// EPI 0: z = tanh(acc + hp[b][c] + W_b[c]) -> bf16 [r][c]
// EPI 1: scores = acc + V_b[c]            -> f32  [r][c]
// EPI 2: xproj  = acc + b_i[c]            -> bf16 [mat][t][b][c]
template <int EPI, bool ABF16>
__global__ __launch_bounds__(512) void gemm_k(
    const void* __restrict__ Aab,
    const float* __restrict__ W0, const float* __restrict__ W1, const float* __restrict__ W2,
    int wstride, int wcoloff,
    const float* __restrict__ bv0, const float* __restrict__ bv1, const float* __restrict__ bv2,
    const float* __restrict__ hp, const float* __restrict__ Wb,
    void* __restrict__ outv) {
    __shared__ __align__(16) unsigned short As[128 * 256];
    __shared__ __align__(16) unsigned short Bs[64 * 256];

    int tid = threadIdx.x;
    int bx = blockIdx.x, by = blockIdx.y;
    int mat = (EPI == 2) ? (by >> 2) : 0;
    int cb  = (EPI == 2) ? (by & 3) : by;
    int rowBase = bx * 128, colBase = cb * 64;
    const float* W  = (mat == 0) ? W0 : ((mat == 1) ? W1 : W2);
    const float* bv = (mat == 0) ? bv0 : ((mat == 1) ? bv1 : bv2);

    // stage A: 128 rows x 32 chunks(16B), swizzled g ^= (r&7)
    if (ABF16) {
        const unsigned short* A = (const unsigned short*)Aab;
#pragma unroll
        for (int i = 0; i < 8; i++) {
            int idx = i * 512 + tid, r = idx >> 5, g = idx & 31, gs = g ^ (r & 7);
            *(uint4*)&As[r * 256 + gs * 8] =
                *(const uint4*)(A + (((size_t)(rowBase + r)) << 8) + g * 8);
        }
    } else {
        const float* A = (const float*)Aab;
#pragma unroll
        for (int i = 0; i < 8; i++) {
            int idx = i * 512 + tid, r = idx >> 5, g = idx & 31, gs = g ^ (r & 7);
            const float* s = A + (((size_t)(rowBase + r)) << 8) + g * 8;
            float4 f0 = *(const float4*)s, f1 = *(const float4*)(s + 4);
            *(u16x8*)&As[r * 256 + gs * 8] = pack8(f0, f1);
        }
    }
    // stage B: 64 W-rows (output cols) x 32 chunks
#pragma unroll
    for (int i = 0; i < 4; i++) {
        int idx = i * 512 + tid, r = idx >> 5, g = idx & 31, gs = g ^ (r & 7);
        const float* s = W + (size_t)(colBase + r) * wstride + wcoloff + g * 8;
        float4 f0 = *(const float4*)s, f1 = *(const float4*)(s + 4);
        *(u16x8*)&Bs[r * 256 + gs * 8] = pack8(f0, f1);
    }
    __syncthreads();

    int wid = tid >> 6, lane = tid & 63, l15 = lane & 15, grp = lane >> 4;
    int wr = (wid >> 1) * 32, wc = (wid & 1) * 32;
    f32x4 acc[2][2] = {};
#pragma unroll
    for (int kc = 0; kc < 8; kc++) {
        u16x8 a[2], bb[2];
#pragma unroll
        for (int rt = 0; rt < 2; rt++) {
            int r = wr + rt * 16 + l15;
            int gs = (kc * 4 + grp) ^ (r & 7);
            a[rt] = *(const u16x8*)&As[r * 256 + gs * 8];
        }
#pragma unroll
        for (int ct = 0; ct < 2; ct++) {
            int r = wc + ct * 16 + l15;
            int gs = (kc * 4 + grp) ^ (r & 7);
            bb[ct] = *(const u16x8*)&Bs[r * 256 + gs * 8];
        }
#pragma unroll
        for (int rt = 0; rt < 2; rt++)
#pragma unroll
            for (int ct = 0; ct < 2; ct++)
                acc[rt][ct] = mfma16(a[rt], bb[ct], acc[rt][ct]);
    }
    // epilogue: D row = (lane>>4)*4 + i, col = lane&15
#pragma unroll
    for (int rt = 0; rt < 2; rt++)
#pragma unroll
        for (int ct = 0; ct < 2; ct++)
#pragma unroll
            for (int i = 0; i < 4; i++) {
                int rl = wr + rt * 16 + grp * 4 + i;
                int cl = wc + ct * 16 + l15;
                size_t r = (size_t)rowBase + rl;
                int c = colBase + cl;
                float v = acc[rt][ct][i];
                if (EPI == 0) {
                    v = tanh_f(v + hp[(r >> 10) * 256 + c] + Wb[c]);
                    ((unsigned short*)outv)[r * 256 + c] = f2bf(v);
                } else if (EPI == 1) {
                    ((float*)outv)[r * 256 + c] = v + bv[c];
                } else {
                    size_t t = r & 1023, b = r >> 10;
                    ((unsigned short*)outv)[(size_t)mat * 16777216 + (t * 64 + b) * 256 + c] =
                        f2bf(v + bv[c]);
                }
            }
}

// ---------- softmax over T, pass 1: per (b,k) online max/sumexp over a T-chunk ----------
__global__ __launch_bounds__(256) void softmax_pass1(const float* __restrict__ scores,
                                                     float* __restrict__ partMS) {
    int b = blockIdx.x, tc = blockIdx.y, k = threadIdx.x;
    const float* p = scores + ((size_t)b * Tt + tc * 128) * Hh + k;
    float m = -1e30f, S = 0.f;
    for (int i = 0; i < 128; i++) {
        float s = p[(size_t)i * Hh];
        float mn = fmaxf(m, s);
        S = S * __expf(m - mn) + __expf(s - mn);
        m = mn;
    }
    int idx = (b * 8 + tc) * Hh + k;
    partMS[idx * 2] = m;
    partMS[idx * 2 + 1] = S;
}

// ---------- softmax pass 2: combine partials, emit ctx (bf16) and x_attn ----------
__global__ __launch_bounds__(256) void softmax_pass2(const float* __restrict__ scores,
                                                     const float* __restrict__ partMS,
                                                     unsigned short* __restrict__ ctx,
                                                     float* __restrict__ x_attn) {
    int b = blockIdx.x, tc = blockIdx.y;
    int tid = threadIdx.x, w = tid >> 6, lane = tid & 63;
    float mj[4], Sj[4];
#pragma unroll
    for (int j = 0; j < 4; j++) {
        int k = lane + j * 64;
        float m = -1e30f;
#pragma unroll
        for (int c = 0; c < 8; c++)
            m = fmaxf(m, partMS[((b * 8 + c) * Hh + k) * 2]);
        float S = 0.f;
#pragma unroll
        for (int c = 0; c < 8; c++) {
            int idx = (b * 8 + c) * Hh + k;
            S += partMS[idx * 2 + 1] * __expf(partMS[idx * 2] - m);
        }
        mj[j] = m;
        Sj[j] = 1.f / S;
    }
    for (int i = 0; i < 32; i++) {
        int t = tc * 128 + w * 32 + i;
        const float* sp = scores + ((size_t)b * Tt + t) * Hh;
        unsigned short* cp = ctx + ((size_t)b * Tt + t) * Hh;
        float accsm = 0.f;
#pragma unroll
        for (int j = 0; j < 4; j++) {
            int k = lane + j * 64;
            float s = sp[k];
            float sm = __expf(s - mj[j]) * Sj[j];
            accsm += sm;
            cp[k] = f2bf(s * sm);
        }
#pragma unroll
        for (int o = 32; o >= 1; o >>= 1) accsm += __shfl_xor(accsm, o, 64);
        if (lane == 0) x_attn[b * Tt + t] = accsm;
    }
}

// ---------- GRU scan ----------
// R6/R7 post-mortem: inline-asm MFMA failed correctness twice (same structured
// error) -> abandoned; intrinsics only (compiler handles MFMA hazards).
// R5 traffic model: the spilled weight file was re-read from L2 each step
// (~230KB/CU/step at ~56B/cy = ~4100cy), matching 3437cy/step measured. Fix
// within the immovable 128-arch-VGPR budget: w_hn lives in LDS (128KB,
// chunk-XOR swizzle -> conflict-free B-frag reads; also forces 1 WG/CU);
// w_hr/w_hz stay as register fragments (128 regs) COAXED into the AGPR half
// via a value-preserving empty asm ("+a") -- gfx950 MFMA reads B from AGPR.
// Budget: 128 wf + 24 acc AGPR + ~55 arch ~= 207 <= 256.
__global__ __attribute__((amdgpu_flat_work_group_size(512, 512),
                          amdgpu_waves_per_eu(2, 2)))
void scan_gru(
    const unsigned short* __restrict__ xg,
    const float* __restrict__ whr, const float* __restrict__ whz, const float* __restrict__ whn,
    const float* __restrict__ bhn,
    const float* __restrict__ hidden,
    float* __restrict__ outputs, float* __restrict__ hlast) {
    __shared__ __align__(16) unsigned short wn_lds[65536];  // w_hn bf16, swizzled (128KB)
    __shared__ __align__(16) unsigned short hb[2][Hh];      // h double-buffer (bf16)
    int b = blockIdx.x;
    int tid = threadIdx.x, w = tid >> 6, lane = tid & 63;
    int l15 = lane & 15, grp = lane >> 4;

    // stage w_hn -> LDS: 16B chunk (col, c) stored at chunk index (c ^ (col&7))
    for (int it = 0; it < 16; ++it) {
        int q = it * 512 + tid;
        int col = q >> 5, c = q & 31;
        const float* s = whn + (size_t)col * Hh + c * 8;
        float4 f0 = *(const float4*)s, f1 = *(const float4*)(s + 4);
        *(u16x8*)&wn_lds[col * 256 + ((c ^ (col & 7)) * 8)] = pack8(f0, f1);
    }

    // w_hr / w_hz fragments: wave owns cols [32w, 32w+32), 2 col-tiles x 8 K-chunks
    u16x8 wfr[2][8], wfz[2][8];
#pragma unroll
    for (int ct = 0; ct < 2; ct++) {
        int col = w * 32 + ct * 16 + l15;
#pragma unroll
        for (int kc = 0; kc < 8; kc++) {
            const float* s1 = whr + (size_t)col * Hh + kc * 32 + grp * 8;
            wfr[ct][kc] = pack8(*(const float4*)s1, *(const float4*)(s1 + 4));
            const float* s2 = whz + (size_t)col * Hh + kc * 32 + grp * 8;
            wfz[ct][kc] = pack8(*(const float4*)s2, *(const float4*)(s2 + 4));
        }
    }
    // Coax the 32 fragments (128 regs) into the AGPR half of the unified RF.
    // Empty asm, "+a" ties: value-preserving, no instructions emitted.
    asm volatile("" : "+a"(wfr[0][0]), "+a"(wfr[0][1]), "+a"(wfr[0][2]), "+a"(wfr[0][3]),
                      "+a"(wfr[0][4]), "+a"(wfr[0][5]), "+a"(wfr[0][6]), "+a"(wfr[0][7]));
    asm volatile("" : "+a"(wfr[1][0]), "+a"(wfr[1][1]), "+a"(wfr[1][2]), "+a"(wfr[1][3]),
                      "+a"(wfr[1][4]), "+a"(wfr[1][5]), "+a"(wfr[1][6]), "+a"(wfr[1][7]));
    asm volatile("" : "+a"(wfz[0][0]), "+a"(wfz[0][1]), "+a"(wfz[0][2]), "+a"(wfz[0][3]),
                      "+a"(wfz[0][4]), "+a"(wfz[0][5]), "+a"(wfz[0][6]), "+a"(wfz[0][7]));
    asm volatile("" : "+a"(wfz[1][0]), "+a"(wfz[1][1]), "+a"(wfz[1][2]), "+a"(wfz[1][3]),
                      "+a"(wfz[1][4]), "+a"(wfz[1][5]), "+a"(wfz[1][6]), "+a"(wfz[1][7]));

    int col0 = w * 32 + l15, col1 = col0 + 16;
    int nb0 = col0 * 256, nx0s = col0 & 7;   // wn_lds bases/swizzle for the two col-tiles
    int nb1 = col1 * 256, nx1s = col1 & 7;
    float bhn0 = 0.f, bhn1 = 0.f, hp0 = 0.f, hp1 = 0.f;
    if (lane < 16) {
        bhn0 = bhn[col0];
        bhn1 = bhn[col1];
        hp0 = hidden[b * Hh + col0];
        hp1 = hidden[b * Hh + col1];
        hb[0][col0] = f2bf(hp0);
        hb[0][col1] = f2bf(hp1);
        outputs[((size_t)b * Tt) * Hh + col0] = hp0;  // outputs[:,0,:] = h0 exact
        outputs[((size_t)b * Tt) * Hh + col1] = hp1;
    }
    const unsigned short* xr = xg;
    const unsigned short* xz = xg + 16777216;
    const unsigned short* xn = xg + 33554432;
    unsigned short px0 = 0, px1 = 0, px2 = 0, px3 = 0, px4 = 0, px5 = 0;
    if (lane < 16) {
        size_t off = ((size_t)64 + b) * Hh;  // t=1
        px0 = xr[off + col0]; px1 = xr[off + col1];
        px2 = xz[off + col0]; px3 = xz[off + col1];
        px4 = xn[off + col0]; px5 = xn[off + col1];
    }
    __syncthreads();

    int p = 0;
    for (int t = 1; t < Tt; t++) {
        unsigned short cx0 = px0, cx1 = px1, cx2 = px2, cx3 = px3, cx4 = px4, cx5 = px5;
        int tnext = (t + 1 < Tt) ? t + 1 : t;
        if (lane < 16) {  // prefetch next step (latency hidden under MFMAs)
            size_t off = ((size_t)tnext * 64 + b) * Hh;
            px0 = xr[off + col0]; px1 = xr[off + col1];
            px2 = xz[off + col0]; px3 = xz[off + col1];
            px4 = xn[off + col0]; px5 = xn[off + col1];
        }
        f32x4 ar0 = {0.f, 0.f, 0.f, 0.f}, ar1 = {0.f, 0.f, 0.f, 0.f};
        f32x4 az0 = {0.f, 0.f, 0.f, 0.f}, az1 = {0.f, 0.f, 0.f, 0.f};
        f32x4 an0 = {0.f, 0.f, 0.f, 0.f}, an1 = {0.f, 0.f, 0.f, 0.f};
#pragma unroll
        for (int kc = 0; kc < 8; kc++) {
            u16x8 af = *(const u16x8*)&hb[p][kc * 32 + grp * 8];  // broadcast read
            ar0 = mfma16(af, wfr[0][kc], ar0);
            ar1 = mfma16(af, wfr[1][kc], ar1);
            az0 = mfma16(af, wfz[0][kc], az0);
            az1 = mfma16(af, wfz[1][kc], az1);
            int c = kc * 4 + grp;
            u16x8 wn0 = *(const u16x8*)&wn_lds[nb0 + ((c ^ nx0s) * 8)];
            u16x8 wn1 = *(const u16x8*)&wn_lds[nb1 + ((c ^ nx1s) * 8)];
            an0 = mfma16(af, wn0, an0);
            an1 = mfma16(af, wn1, an1);
        }
        if (lane < 16) {
            float r0 = sigm(bf2f(cx0) + ar0[0]);   // b_ir+b_hr pre-folded
            float r1 = sigm(bf2f(cx1) + ar1[0]);
            float z0 = sigm(bf2f(cx2) + az0[0]);   // b_iz+b_hz pre-folded
            float z1 = sigm(bf2f(cx3) + az1[0]);
            float n0 = tanh_f(bf2f(cx4) + r0 * (an0[0] + bhn0));
            float n1 = tanh_f(bf2f(cx5) + r1 * (an1[0] + bhn1));
            float hn0 = (1.f - z0) * n0 + z0 * hp0;
            float hn1 = (1.f - z1) * n1 + z1 * hp1;
            hb[p ^ 1][col0] = f2bf(hn0);   // write the OTHER buffer: no read-WAR
            hb[p ^ 1][col1] = f2bf(hn1);
            size_t ro = ((size_t)b * Tt + t) * Hh;
            outputs[ro + col0] = hn0;      // fire-and-forget (no vmcnt drain below)
            outputs[ro + col1] = hn1;
            hp0 = hn0;
            hp1 = hn1;
        }
        p ^= 1;
        // LDS-only barrier: do NOT drain vmcnt (stores + prefetch stay in flight).
        asm volatile("s_waitcnt lgkmcnt(0)" ::: "memory");
        __builtin_amdgcn_s_barrier();
        asm volatile("" ::: "memory");
    }
    if (lane < 16) {
        hlast[b * Hh + col0] = hp0;
        hlast[b * Hh + col1] = hp1;
    }
}

// ---------- launch ----------
extern "C" void kernel_launch(void* const* d_in, const int* in_sizes, int n_in,
                              void* d_out, int out_size, void* d_ws, size_t ws_size,
                              hipStream_t stream) {
    const float* inputs = (const float*)d_in[0];
    const float* hidden = (const float*)d_in[1];
    const float* W_w  = (const float*)d_in[2];
    const float* W_b  = (const float*)d_in[3];
    const float* V_w  = (const float*)d_in[4];
    const float* V_b  = (const float*)d_in[5];
    const float* w_ir = (const float*)d_in[6];
    const float* w_iz = (const float*)d_in[7];
    const float* w_in = (const float*)d_in[8];
    const float* b_ir = (const float*)d_in[9];
    const float* b_iz = (const float*)d_in[10];
    const float* b_in = (const float*)d_in[11];
    const float* w_hr = (const float*)d_in[12];
    const float* w_hz = (const float*)d_in[13];
    const float* w_hn = (const float*)d_in[14];
    const float* b_hr = (const float*)d_in[15];
    const float* b_hz = (const float*)d_in[16];
    const float* b_hn = (const float*)d_in[17];

    // workspace layout (~135.5 MB)
    float* hp = (float*)d_ws;                                  // 65536 f32
    float* partMS = hp + 65536;                                // 64*8*256*2 f32
    float* cbias = partMS + 262144;                            // 512 f32
    unsigned short* zbuf = (unsigned short*)(cbias + 512);     // 16.7M bf16
    unsigned short* ctx = zbuf;                                // alias: z dead after GEMM2
    unsigned short* xgb = zbuf + 16777216;                     // 3 x 16.7M bf16

    float* scores  = (float*)d_out;         // scores staged in outputs slot (dead before scan)
    float* outputs = (float*)d_out;
    float* hlast   = outputs + 16777216;
    float* x_attn  = hlast + 16384;

    hp_kernel<<<64, 256, 0, stream>>>(hidden, W_w, hp);
    bias_prep<<<1, 256, 0, stream>>>(b_ir, b_hr, b_iz, b_hz, cbias);

    gemm_k<0, false><<<dim3(512, 4), 512, 0, stream>>>(
        inputs, W_w, nullptr, nullptr, 512, 256,
        nullptr, nullptr, nullptr, hp, W_b, zbuf);

    gemm_k<1, true><<<dim3(512, 4), 512, 0, stream>>>(
        zbuf, V_w, nullptr, nullptr, 256, 0,
        V_b, nullptr, nullptr, nullptr, nullptr, scores);

    softmax_pass1<<<dim3(64, 8), 256, 0, stream>>>(scores, partMS);
    softmax_pass2<<<dim3(64, 8), 256, 0, stream>>>(scores, partMS, ctx, x_attn);

    gemm_k<2, true><<<dim3(512, 12), 512, 0, stream>>>(
        ctx, w_ir, w_iz, w_in, 256, 0,
        cbias, cbias + 256, b_in, nullptr, nullptr, xgb);

    scan_gru<<<64, 512, 0, stream>>>(
        xgb, w_hr, w_hz, w_hn, b_hn, hidden, outputs, hlast);
}

// Round 9
// 1476.774 us; speedup vs baseline: 1.8201x; 1.1086x over previous
//
#include <hip/hip_runtime.h>

#define DEVI __device__ __forceinline__

typedef float  f32x4  __attribute__((ext_vector_type(4)));
typedef __bf16 bf16x8 __attribute__((ext_vector_type(8)));
typedef unsigned short u16x8 __attribute__((ext_vector_type(8)));

// ---------- helpers ----------
DEVI unsigned short f2bf(float f) {
    unsigned u = __builtin_bit_cast(unsigned, f);
    unsigned r = (u + 0x7fffu + ((u >> 16) & 1u)) >> 16;
    return (unsigned short)r;
}
DEVI float bf2f(unsigned short s) {
    return __builtin_bit_cast(float, (unsigned)s << 16);
}
DEVI u16x8 pack8(float4 a, float4 b) {
    u16x8 p;
    p[0] = f2bf(a.x); p[1] = f2bf(a.y); p[2] = f2bf(a.z); p[3] = f2bf(a.w);
    p[4] = f2bf(b.x); p[5] = f2bf(b.y); p[6] = f2bf(b.z); p[7] = f2bf(b.w);
    return p;
}
DEVI f32x4 mfma16(u16x8 a, u16x8 b, f32x4 c) {
    return __builtin_amdgcn_mfma_f32_16x16x32_bf16(
        __builtin_bit_cast(bf16x8, a), __builtin_bit_cast(bf16x8, b), c, 0, 0, 0);
}
DEVI float sigm(float x)   { return 1.f / (1.f + __expf(-x)); }
DEVI float tanh_f(float x) { return 1.f - 2.f / (1.f + __expf(2.f * x)); }

// dims
#define Hh 256
#define Bb 64
#define Tt 1024
#define MROWS (Bb * Tt)   // 65536

// ---------- K0: hp[b][k] = sum_h hidden[b][h] * W_w[k][h] (first H cols) ----------
__global__ __launch_bounds__(256) void hp_kernel(const float* __restrict__ hid,
                                                 const float* __restrict__ Ww,
                                                 float* __restrict__ hp) {
    int b = blockIdx.x, k = threadIdx.x;
    __shared__ __align__(16) float hs[Hh];
    hs[k] = hid[b * Hh + k];
    __syncthreads();
    const float4* w4 = (const float4*)(Ww + (size_t)k * 512);
    const float4* h4 = (const float4*)hs;
    float acc = 0.f;
#pragma unroll 8
    for (int i = 0; i < 64; i++) {
        float4 a = w4[i], x = h4[i];
        acc += a.x * x.x + a.y * x.y + a.z * x.z + a.w * x.w;
    }
    hp[b * Hh + k] = acc;
}

// ---------- bias prep: cb[0][k]=b_ir+b_hr, cb[1][k]=b_iz+b_hz ----------
__global__ __launch_bounds__(256) void bias_prep(const float* __restrict__ b_ir,
                                                 const float* __restrict__ b_hr,
                                                 const float* __restrict__ b_iz,
                                                 const float* __restrict__ b_hz,
                                                 float* __restrict__ cb) {
    int k = threadIdx.x;
    cb[k] = b_ir[k] + b_hr[k];
    cb[256 + k] = b_iz[k] + b_hz[k];
}

// ---------- GEMM: OUT = epilogue( A(65536x256) @ W^T )  BM=128 BN=64 K=256 ----------
// EPI 0: z = tanh(acc + hp[b][c] + W_b[c]) -> bf16 [r][c]
// EPI 1: scores = acc + V_b[c]            -> f32  [r][c]
// EPI 2: xproj  = acc + b_i[c]            -> bf16 [mat][t][b][c]
template <int EPI, bool ABF16>
__global__ __launch_bounds__(512) void gemm_k(
    const void* __restrict__ Aab,
    const float* __restrict__ W0, const float* __restrict__ W1, const float* __restrict__ W2,
    int wstride, int wcoloff,
    const float* __restrict__ bv0, const float* __restrict__ bv1, const float* __restrict__ bv2,
    const float* __restrict__ hp, const float* __restrict__ Wb,
    void* __restrict__ outv) {
    __shared__ __align__(16) unsigned short As[128 * 256];
    __shared__ __align__(16) unsigned short Bs[64 * 256];

    int tid = threadIdx.x;
    int bx = blockIdx.x, by = blockIdx.y;
    int mat = (EPI == 2) ? (by >> 2) : 0;
    int cb  = (EPI == 2) ? (by & 3) : by;
    int rowBase = bx * 128, colBase = cb * 64;
    const float* W  = (mat == 0) ? W0 : ((mat == 1) ? W1 : W2);
    const float* bv = (mat == 0) ? bv0 : ((mat == 1) ? bv1 : bv2);

    // stage A: 128 rows x 32 chunks(16B), swizzled g ^= (r&7)
    if (ABF16) {
        const unsigned short* A = (const unsigned short*)Aab;
#pragma unroll
        for (int i = 0; i < 8; i++) {
            int idx = i * 512 + tid, r = idx >> 5, g = idx & 31, gs = g ^ (r & 7);
            *(uint4*)&As[r * 256 + gs * 8] =
                *(const uint4*)(A + (((size_t)(rowBase + r)) << 8) + g * 8);
        }
    } else {
        const float* A = (const float*)Aab;
#pragma unroll
        for (int i = 0; i < 8; i++) {
            int idx = i * 512 + tid, r = idx >> 5, g = idx & 31, gs = g ^ (r & 7);
            const float* s = A + (((size_t)(rowBase + r)) << 8) + g * 8;
            float4 f0 = *(const float4*)s, f1 = *(const float4*)(s + 4);
            *(u16x8*)&As[r * 256 + gs * 8] = pack8(f0, f1);
        }
    }
    // stage B: 64 W-rows (output cols) x 32 chunks
#pragma unroll
    for (int i = 0; i < 4; i++) {
        int idx = i * 512 + tid, r = idx >> 5, g = idx & 31, gs = g ^ (r & 7);
        const float* s = W + (size_t)(colBase + r) * wstride + wcoloff + g * 8;
        float4 f0 = *(const float4*)s, f1 = *(const float4*)(s + 4);
        *(u16x8*)&Bs[r * 256 + gs * 8] = pack8(f0, f1);
    }
    __syncthreads();

    int wid = tid >> 6, lane = tid & 63, l15 = lane & 15, grp = lane >> 4;
    int wr = (wid >> 1) * 32, wc = (wid & 1) * 32;
    f32x4 acc[2][2] = {};
#pragma unroll
    for (int kc = 0; kc < 8; kc++) {
        u16x8 a[2], bb[2];
#pragma unroll
        for (int rt = 0; rt < 2; rt++) {
            int r = wr + rt * 16 + l15;
            int gs = (kc * 4 + grp) ^ (r & 7);
            a[rt] = *(const u16x8*)&As[r * 256 + gs * 8];
        }
#pragma unroll
        for (int ct = 0; ct < 2; ct++) {
            int r = wc + ct * 16 + l15;
            int gs = (kc * 4 + grp) ^ (r & 7);
            bb[ct] = *(const u16x8*)&Bs[r * 256 + gs * 8];
        }
#pragma unroll
        for (int rt = 0; rt < 2; rt++)
#pragma unroll
            for (int ct = 0; ct < 2; ct++)
                acc[rt][ct] = mfma16(a[rt], bb[ct], acc[rt][ct]);
    }
    // epilogue: D row = (lane>>4)*4 + i, col = lane&15
#pragma unroll
    for (int rt = 0; rt < 2; rt++)
#pragma unroll
        for (int ct = 0; ct < 2; ct++)
#pragma unroll
            for (int i = 0; i < 4; i++) {
                int rl = wr + rt * 16 + grp * 4 + i;
                int cl = wc + ct * 16 + l15;
                size_t r = (size_t)rowBase + rl;
                int c = colBase + cl;
                float v = acc[rt][ct][i];
                if (EPI == 0) {
                    v = tanh_f(v + hp[(r >> 10) * 256 + c] + Wb[c]);
                    ((unsigned short*)outv)[r * 256 + c] = f2bf(v);
                } else if (EPI == 1) {
                    ((float*)outv)[r * 256 + c] = v + bv[c];
                } else {
                    size_t t = r & 1023, b = r >> 10;
                    ((unsigned short*)outv)[(size_t)mat * 16777216 + (t * 64 + b) * 256 + c] =
                        f2bf(v + bv[c]);
                }
            }
}

// ---------- softmax over T, pass 1: per (b,k) online max/sumexp over a T-chunk ----------
__global__ __launch_bounds__(256) void softmax_pass1(const float* __restrict__ scores,
                                                     float* __restrict__ partMS) {
    int b = blockIdx.x, tc = blockIdx.y, k = threadIdx.x;
    const float* p = scores + ((size_t)b * Tt + tc * 128) * Hh + k;
    float m = -1e30f, S = 0.f;
    for (int i = 0; i < 128; i++) {
        float s = p[(size_t)i * Hh];
        float mn = fmaxf(m, s);
        S = S * __expf(m - mn) + __expf(s - mn);
        m = mn;
    }
    int idx = (b * 8 + tc) * Hh + k;
    partMS[idx * 2] = m;
    partMS[idx * 2 + 1] = S;
}

// ---------- softmax pass 2: combine partials, emit ctx (bf16) and x_attn ----------
__global__ __launch_bounds__(256) void softmax_pass2(const float* __restrict__ scores,
                                                     const float* __restrict__ partMS,
                                                     unsigned short* __restrict__ ctx,
                                                     float* __restrict__ x_attn) {
    int b = blockIdx.x, tc = blockIdx.y;
    int tid = threadIdx.x, w = tid >> 6, lane = tid & 63;
    float mj[4], Sj[4];
#pragma unroll
    for (int j = 0; j < 4; j++) {
        int k = lane + j * 64;
        float m = -1e30f;
#pragma unroll
        for (int c = 0; c < 8; c++)
            m = fmaxf(m, partMS[((b * 8 + c) * Hh + k) * 2]);
        float S = 0.f;
#pragma unroll
        for (int c = 0; c < 8; c++) {
            int idx = (b * 8 + c) * Hh + k;
            S += partMS[idx * 2 + 1] * __expf(partMS[idx * 2] - m);
        }
        mj[j] = m;
        Sj[j] = 1.f / S;
    }
    for (int i = 0; i < 32; i++) {
        int t = tc * 128 + w * 32 + i;
        const float* sp = scores + ((size_t)b * Tt + t) * Hh;
        unsigned short* cp = ctx + ((size_t)b * Tt + t) * Hh;
        float accsm = 0.f;
#pragma unroll
        for (int j = 0; j < 4; j++) {
            int k = lane + j * 64;
            float s = sp[k];
            float sm = __expf(s - mj[j]) * Sj[j];
            accsm += sm;
            cp[k] = f2bf(s * sm);
        }
#pragma unroll
        for (int o = 32; o >= 1; o >>= 1) accsm += __shfl_xor(accsm, o, 64);
        if (lane == 0) x_attn[b * Tt + t] = accsm;
    }
}

// ---------- GRU scan ----------
// R8 post-mortem: spill gone (WRITE 106.8->65.6MB) but SQ_LDS_BANK_CONFLICT
// jumped to 3.35e7 (~512cy/step/CU): col-major wn_lds put all 16 cols of a
// fragment read at bank 0 (col stride 512B = 0 mod 128B). R9: FRAGMENT-MAJOR
// layout -- each B-fragment stored contiguously, frag=(w*2+ct)*8+kc, lane's
// 16B at frag*1024+lane*16 -> wave read = one linear 1KB sweep, ZERO
// conflicts, and per-kc address is base + immediate offset (kills XOR VALU).
// Also: epilogue spread to 32 lanes (3 shuffles move col1 accs to lanes
// 16-31; each lane computes ONE column's gate chain).
__global__ __attribute__((amdgpu_flat_work_group_size(512, 512),
                          amdgpu_waves_per_eu(2, 2)))
void scan_gru(
    const unsigned short* __restrict__ xg,
    const float* __restrict__ whr, const float* __restrict__ whz, const float* __restrict__ whn,
    const float* __restrict__ bhn,
    const float* __restrict__ hidden,
    float* __restrict__ outputs, float* __restrict__ hlast) {
    __shared__ __align__(16) unsigned short wn_lds[65536];  // w_hn, fragment-major (128KB)
    __shared__ __align__(16) unsigned short hb[2][Hh];      // h double-buffer (bf16)
    int b = blockIdx.x;
    int tid = threadIdx.x, w = tid >> 6, lane = tid & 63;
    int grp = lane >> 4;

    // stage w_hn -> LDS fragment-major: frag=(col>>4)*8+kc holds 64 lanes x 16B;
    // lane slot (grp*16+l15) <- whn[col=tile*16+l15][kc*32+grp*8 ..+8].
    // q -> (frag, lslot) so LDS writes are linear (conflict-free).
    for (int it = 0; it < 16; ++it) {
        int q = it * 512 + tid;
        int frag = q >> 6, lslot = q & 63;
        int col = ((frag >> 3) << 4) | (lslot & 15);
        int koff = (frag & 7) * 32 + (lslot >> 4) * 8;
        const float* s = whn + (size_t)col * Hh + koff;
        *(u16x8*)&wn_lds[frag * 512 + lslot * 8] = pack8(*(const float4*)s, *(const float4*)(s + 4));
    }

    // w_hr / w_hz fragments: wave owns cols [32w, 32w+32), 2 col-tiles x 8 K-chunks
    u16x8 wfr[2][8], wfz[2][8];
#pragma unroll
    for (int ct = 0; ct < 2; ct++) {
        int col = w * 32 + ct * 16 + (lane & 15);
#pragma unroll
        for (int kc = 0; kc < 8; kc++) {
            const float* s1 = whr + (size_t)col * Hh + kc * 32 + grp * 8;
            wfr[ct][kc] = pack8(*(const float4*)s1, *(const float4*)(s1 + 4));
            const float* s2 = whz + (size_t)col * Hh + kc * 32 + grp * 8;
            wfz[ct][kc] = pack8(*(const float4*)s2, *(const float4*)(s2 + 4));
        }
    }
    // Coax the 32 fragments (128 regs) into the AGPR half of the unified RF
    // (value-preserving empty asm; R8 verified: kills the spill).
    asm volatile("" : "+a"(wfr[0][0]), "+a"(wfr[0][1]), "+a"(wfr[0][2]), "+a"(wfr[0][3]),
                      "+a"(wfr[0][4]), "+a"(wfr[0][5]), "+a"(wfr[0][6]), "+a"(wfr[0][7]));
    asm volatile("" : "+a"(wfr[1][0]), "+a"(wfr[1][1]), "+a"(wfr[1][2]), "+a"(wfr[1][3]),
                      "+a"(wfr[1][4]), "+a"(wfr[1][5]), "+a"(wfr[1][6]), "+a"(wfr[1][7]));
    asm volatile("" : "+a"(wfz[0][0]), "+a"(wfz[0][1]), "+a"(wfz[0][2]), "+a"(wfz[0][3]),
                      "+a"(wfz[0][4]), "+a"(wfz[0][5]), "+a"(wfz[0][6]), "+a"(wfz[0][7]));
    asm volatile("" : "+a"(wfz[1][0]), "+a"(wfz[1][1]), "+a"(wfz[1][2]), "+a"(wfz[1][3]),
                      "+a"(wfz[1][4]), "+a"(wfz[1][5]), "+a"(wfz[1][6]), "+a"(wfz[1][7]));

    // per-lane state: lanes 0-15 own col0 block, lanes 16-31 own col1 block
    int mycol = w * 32 + (lane & 31);
    int wnb = (w * 16) * 512 + lane * 8;  // fragment-major base (elems); +8*512 for ct=1
    float bhnS = 0.f, hpS = 0.f;
    if (lane < 32) {
        bhnS = bhn[mycol];
        hpS = hidden[b * Hh + mycol];
        hb[0][mycol] = f2bf(hpS);
        outputs[((size_t)b * Tt) * Hh + mycol] = hpS;  // outputs[:,0,:] = h0 exact
    }
    const unsigned short* xr = xg;
    const unsigned short* xz = xg + 16777216;
    const unsigned short* xn = xg + 33554432;
    unsigned short pxr = 0, pxz = 0, pxn = 0;
    if (lane < 32) {
        size_t off = ((size_t)64 + b) * Hh + mycol;  // t=1
        pxr = xr[off]; pxz = xz[off]; pxn = xn[off];
    }
    __syncthreads();

    int p = 0;
    for (int t = 1; t < Tt; t++) {
        unsigned short cxr = pxr, cxz = pxz, cxn = pxn;
        int tnext = (t + 1 < Tt) ? t + 1 : t;
        if (lane < 32) {  // prefetch next step (latency hidden under MFMAs)
            size_t off = ((size_t)tnext * 64 + b) * Hh + mycol;
            pxr = xr[off]; pxz = xz[off]; pxn = xn[off];
        }
        f32x4 ar0 = {0.f, 0.f, 0.f, 0.f}, ar1 = {0.f, 0.f, 0.f, 0.f};
        f32x4 az0 = {0.f, 0.f, 0.f, 0.f}, az1 = {0.f, 0.f, 0.f, 0.f};
        f32x4 an0 = {0.f, 0.f, 0.f, 0.f}, an1 = {0.f, 0.f, 0.f, 0.f};
#pragma unroll
        for (int kc = 0; kc < 8; kc++) {
            u16x8 af = *(const u16x8*)&hb[p][kc * 32 + grp * 8];  // broadcast read
            ar0 = mfma16(af, wfr[0][kc], ar0);
            ar1 = mfma16(af, wfr[1][kc], ar1);
            az0 = mfma16(af, wfz[0][kc], az0);
            az1 = mfma16(af, wfz[1][kc], az1);
            u16x8 wn0 = *(const u16x8*)&wn_lds[wnb + kc * 512];           // linear sweep
            u16x8 wn1 = *(const u16x8*)&wn_lds[wnb + 8 * 512 + kc * 512]; // imm offsets
            an0 = mfma16(af, wn0, an0);
            an1 = mfma16(af, wn1, an1);
        }
        // move col1-block accs (row 0 lives in lanes 0-15) to lanes 16-31
        float vr = __shfl(ar1[0], lane & 15);
        float vz = __shfl(az1[0], lane & 15);
        float vn = __shfl(an1[0], lane & 15);
        float gr = (lane < 16) ? ar0[0] : vr;
        float gz = (lane < 16) ? az0[0] : vz;
        float gn = (lane < 16) ? an0[0] : vn;
        if (lane < 32) {
            float r0 = sigm(bf2f(cxr) + gr);              // b_ir+b_hr pre-folded
            float z0 = sigm(bf2f(cxz) + gz);              // b_iz+b_hz pre-folded
            float n0 = tanh_f(bf2f(cxn) + r0 * (gn + bhnS));
            float hn = (1.f - z0) * n0 + z0 * hpS;
            hb[p ^ 1][mycol] = f2bf(hn);   // write the OTHER buffer: no read-WAR
            outputs[((size_t)b * Tt + t) * Hh + mycol] = hn;  // fire-and-forget
            hpS = hn;
        }
        p ^= 1;
        // LDS-only barrier: do NOT drain vmcnt (stores + prefetch stay in flight).
        asm volatile("s_waitcnt lgkmcnt(0)" ::: "memory");
        __builtin_amdgcn_s_barrier();
        asm volatile("" ::: "memory");
    }
    if (lane < 32) {
        hlast[b * Hh + mycol] = hpS;
    }
}

// ---------- launch ----------
extern "C" void kernel_launch(void* const* d_in, const int* in_sizes, int n_in,
                              void* d_out, int out_size, void* d_ws, size_t ws_size,
                              hipStream_t stream) {
    const float* inputs = (const float*)d_in[0];
    const float* hidden = (const float*)d_in[1];
    const float* W_w  = (const float*)d_in[2];
    const float* W_b  = (const float*)d_in[3];
    const float* V_w  = (const float*)d_in[4];
    const float* V_b  = (const float*)d_in[5];
    const float* w_ir = (const float*)d_in[6];
    const float* w_iz = (const float*)d_in[7];
    const float* w_in = (const float*)d_in[8];
    const float* b_ir = (const float*)d_in[9];
    const float* b_iz = (const float*)d_in[10];
    const float* b_in = (const float*)d_in[11];
    const float* w_hr = (const float*)d_in[12];
    const float* w_hz = (const float*)d_in[13];
    const float* w_hn = (const float*)d_in[14];
    const float* b_hr = (const float*)d_in[15];
    const float* b_hz = (const float*)d_in[16];
    const float* b_hn = (const float*)d_in[17];

    // workspace layout (~135.5 MB)
    float* hp = (float*)d_ws;                                  // 65536 f32
    float* partMS = hp + 65536;                                // 64*8*256*2 f32
    float* cbias = partMS + 262144;                            // 512 f32
    unsigned short* zbuf = (unsigned short*)(cbias + 512);     // 16.7M bf16
    unsigned short* ctx = zbuf;                                // alias: z dead after GEMM2
    unsigned short* xgb = zbuf + 16777216;                     // 3 x 16.7M bf16

    float* scores  = (float*)d_out;         // scores staged in outputs slot (dead before scan)
    float* outputs = (float*)d_out;
    float* hlast   = outputs + 16777216;
    float* x_attn  = hlast + 16384;

    hp_kernel<<<64, 256, 0, stream>>>(hidden, W_w, hp);
    bias_prep<<<1, 256, 0, stream>>>(b_ir, b_hr, b_iz, b_hz, cbias);

    gemm_k<0, false><<<dim3(512, 4), 512, 0, stream>>>(
        inputs, W_w, nullptr, nullptr, 512, 256,
        nullptr, nullptr, nullptr, hp, W_b, zbuf);

    gemm_k<1, true><<<dim3(512, 4), 512, 0, stream>>>(
        zbuf, V_w, nullptr, nullptr, 256, 0,
        V_b, nullptr, nullptr, nullptr, nullptr, scores);

    softmax_pass1<<<dim3(64, 8), 256, 0, stream>>>(scores, partMS);
    softmax_pass2<<<dim3(64, 8), 256, 0, stream>>>(scores, partMS, ctx, x_attn);

    gemm_k<2, true><<<dim3(512, 12), 512, 0, stream>>>(
        ctx, w_ir, w_iz, w_in, 256, 0,
        cbias, cbias + 256, b_in, nullptr, nullptr, xgb);

    scan_gru<<<64, 512, 0, stream>>>(
        xgb, w_hr, w_hz, w_hn, b_hn, hidden, outputs, hlast);
}